// Round 1
// baseline (1132.899 us; speedup 1.0000x reference)
//
#include <hip/hip_runtime.h>
#include <hip/hip_bf16.h>

typedef __bf16 bf16;
typedef __attribute__((ext_vector_type(8))) __bf16 bf16x8;
typedef __attribute__((ext_vector_type(4))) float f32x4;

#define B_ 128
#define L_ 8
#define T_ 48
#define E_ 512
#define H_ 512
#define V_ 10000

__device__ __forceinline__ float sigf(float x) { return 1.f / (1.f + expf(-x)); }

__device__ __forceinline__ bf16x8 bzero8() {
  bf16x8 z;
  #pragma unroll
  for (int q = 0; q < 8; ++q) z[q] = (bf16)0.f;
  return z;
}

// ---------------------------------------------------------------------------
// Prep: cast weights f32->bf16, gather embeddings for kws (rows l*128+b) and
// poem (rows t*128+b), zero encoder c-state and initial h.
// ---------------------------------------------------------------------------
__global__ void prep_kernel(
    const int* __restrict__ kws, const int* __restrict__ poem,
    const float* __restrict__ emb,
    const float* __restrict__ eWih, const float* __restrict__ eWhh,
    const float* __restrict__ dWih, const float* __restrict__ dWhh,
    const float* __restrict__ outW,
    bf16* __restrict__ WihE, bf16* __restrict__ WhhE,
    bf16* __restrict__ WihD, bf16* __restrict__ WhhD,
    bf16* __restrict__ outWb,
    bf16* __restrict__ Xenc, bf16* __restrict__ Xdec,
    float* __restrict__ cE, bf16* __restrict__ hbE0)
{
  const long SW = 1048576;      // 2048*512
  const long SOW = 10240000;    // 10000*1024
  const long SXE = 524288;      // 1024*512
  const long SXD = 3145728;     // 6144*512
  const long SZ = 65536;        // 128*512
  const long total = 4 * SW + SOW + SXE + SXD + SZ;
  for (long i = blockIdx.x * (long)blockDim.x + threadIdx.x; i < total;
       i += (long)gridDim.x * blockDim.x) {
    long j = i;
    if (j < SW) { WihE[j] = (bf16)eWih[j]; continue; } j -= SW;
    if (j < SW) { WhhE[j] = (bf16)eWhh[j]; continue; } j -= SW;
    if (j < SW) { WihD[j] = (bf16)dWih[j]; continue; } j -= SW;
    if (j < SW) { WhhD[j] = (bf16)dWhh[j]; continue; } j -= SW;
    if (j < SOW) { outWb[j] = (bf16)outW[j]; continue; } j -= SOW;
    if (j < SXE) {
      int e = (int)(j & 511); int b = (int)((j >> 9) & 127); int l = (int)(j >> 16);
      int tok = kws[b * L_ + l];
      Xenc[j] = (bf16)emb[(long)tok * 512 + e];
      continue;
    } j -= SXE;
    if (j < SXD) {
      int e = (int)(j & 511); int b = (int)((j >> 9) & 127); int t = (int)(j >> 16);
      int tok = poem[b * T_ + t];
      Xdec[j] = (bf16)emb[(long)tok * 512 + e];
      continue;
    } j -= SXD;
    cE[j] = 0.f; hbE0[j] = (bf16)0.f;
  }
}

// ---------------------------------------------------------------------------
// Generic NT GEMM: C[M,N] = A[M,K] * B[N,K]^T + bias[N]
// A,B bf16; C f32 or bf16; optional scatter to [b][t][V] with row = t*128+b.
// 128x128 tile, BK=32, 4 waves of 64x64, 16x16x32 bf16 MFMA.
// ---------------------------------------------------------------------------
template<bool BF16_OUT, bool SCATTER>
__global__ __launch_bounds__(256) void gemm_nt_kernel(
    const bf16* __restrict__ A, const bf16* __restrict__ Bm,
    const float* __restrict__ bias, void* __restrict__ outp,
    int M, int N, int K)
{
  __shared__ bf16 As[128][40];   // +8 pad: row stride 80B (16B-aligned, bank-friendly)
  __shared__ bf16 Bs[128][40];
  const int tid = threadIdx.x;
  const int lane = tid & 63, wid = tid >> 6;
  const int wm = (wid >> 1) * 64, wn = (wid & 1) * 64;
  const int m0 = blockIdx.y * 128, n0 = blockIdx.x * 128;

  f32x4 acc[4][4];
  #pragma unroll
  for (int mi = 0; mi < 4; ++mi)
    #pragma unroll
    for (int ni = 0; ni < 4; ++ni) {
      acc[mi][ni][0] = 0.f; acc[mi][ni][1] = 0.f;
      acc[mi][ni][2] = 0.f; acc[mi][ni][3] = 0.f;
    }

  const int fr = lane & 15, kg = (lane >> 4) << 3;

  for (int kt = 0; kt < K; kt += 32) {
    #pragma unroll
    for (int rep = 0; rep < 2; ++rep) {
      int idx = (rep * 256 + tid) * 8;
      int r = idx >> 5, c = idx & 31;
      *(bf16x8*)&As[r][c] = *(const bf16x8*)(A + (size_t)(m0 + r) * K + kt + c);
      int rn = n0 + r;
      bf16x8 w = (rn < N) ? *(const bf16x8*)(Bm + (size_t)rn * K + kt + c) : bzero8();
      *(bf16x8*)&Bs[r][c] = w;
    }
    __syncthreads();
    bf16x8 af[4], bfr[4];
    #pragma unroll
    for (int mi = 0; mi < 4; ++mi) af[mi] = *(const bf16x8*)&As[wm + mi * 16 + fr][kg];
    #pragma unroll
    for (int ni = 0; ni < 4; ++ni) bfr[ni] = *(const bf16x8*)&Bs[wn + ni * 16 + fr][kg];
    #pragma unroll
    for (int mi = 0; mi < 4; ++mi)
      #pragma unroll
      for (int ni = 0; ni < 4; ++ni)
        acc[mi][ni] = __builtin_amdgcn_mfma_f32_16x16x32_bf16(af[mi], bfr[ni], acc[mi][ni], 0, 0, 0);
    __syncthreads();
  }

  const int fq = (lane >> 4) * 4;
  #pragma unroll
  for (int mi = 0; mi < 4; ++mi) {
    #pragma unroll
    for (int ni = 0; ni < 4; ++ni) {
      #pragma unroll
      for (int j = 0; j < 4; ++j) {
        int r = m0 + wm + mi * 16 + fq + j;
        int cix = n0 + wn + ni * 16 + fr;
        if (cix < N) {
          float v = acc[mi][ni][j] + bias[cix];
          if (SCATTER) {
            int b = r & 127, t = r >> 7;   // row = t*128+b
            ((float*)outp)[(size_t)b * (T_ * V_) + (size_t)t * V_ + cix] = v;
          } else if (BF16_OUT) {
            ((bf16*)outp)[(size_t)r * N + cix] = (bf16)v;
          } else {
            ((float*)outp)[(size_t)r * N + cix] = v;
          }
        }
      }
    }
  }
}

// ---------------------------------------------------------------------------
// One LSTM step, fused: gates = preG + h_in @ Whh^T, pointwise -> h_out, c.
// Blocks 0..31: GEMM+pointwise (block owns 16 H-columns x all 4 gates).
// Blocks 32..159 (decoder only): attention for step t-1 using h_in, writes
// Hcat row block: [h_{t-1} | ctx_{t-1}] in bf16.
// ---------------------------------------------------------------------------
__global__ __launch_bounds__(256) void step_kernel(
    const bf16* __restrict__ h_in, bf16* __restrict__ h_out,
    float* __restrict__ c_state,
    const bf16* __restrict__ preG,   // [128][2048] for this t (i,f,g,o chunks)
    const bf16* __restrict__ Whh,    // [2048][512]
    bf16* __restrict__ hsEnc_t,      // [128][512] masked (enc only)
    bf16* __restrict__ h0b, float* __restrict__ c0f,
    const int* __restrict__ kw_lens, int t, int is_enc,
    const bf16* __restrict__ hsEnc_all,  // [8][128][512] (dec only)
    bf16* __restrict__ Hcat_prev,        // rows for step t-1 (dec only)
    int do_gemm, int do_attn)
{
  __shared__ bf16 As[128][40];
  __shared__ bf16 Bs[64][40];
  __shared__ float sc[8];
  const int tid = threadIdx.x;
  const int lane = tid & 63, wid = tid >> 6;

  if (blockIdx.x < 32) {
    if (!do_gemm) return;
    const int n0 = blockIdx.x * 16;
    f32x4 acc[2][4];
    #pragma unroll
    for (int mi = 0; mi < 2; ++mi)
      #pragma unroll
      for (int g = 0; g < 4; ++g) {
        acc[mi][g][0] = 0.f; acc[mi][g][1] = 0.f;
        acc[mi][g][2] = 0.f; acc[mi][g][3] = 0.f;
      }
    const int fr = lane & 15, kg = (lane >> 4) << 3;

    for (int kt = 0; kt < 512; kt += 32) {
      #pragma unroll
      for (int rep = 0; rep < 2; ++rep) {
        int idx = (rep * 256 + tid) * 8;
        int r = idx >> 5, c = idx & 31;
        *(bf16x8*)&As[r][c] = *(const bf16x8*)(h_in + (size_t)r * 512 + kt + c);
      }
      {
        int idx = tid * 8;
        int r = idx >> 5, c = idx & 31;     // r in 0..63
        int g = r >> 4, rr = r & 15;
        *(bf16x8*)&Bs[r][c] = *(const bf16x8*)(Whh + (size_t)(g * 512 + n0 + rr) * 512 + kt + c);
      }
      __syncthreads();
      bf16x8 af[2], bg[4];
      #pragma unroll
      for (int mi = 0; mi < 2; ++mi) af[mi] = *(const bf16x8*)&As[wid * 32 + mi * 16 + fr][kg];
      #pragma unroll
      for (int g = 0; g < 4; ++g) bg[g] = *(const bf16x8*)&Bs[g * 16 + fr][kg];
      #pragma unroll
      for (int mi = 0; mi < 2; ++mi)
        #pragma unroll
        for (int g = 0; g < 4; ++g)
          acc[mi][g] = __builtin_amdgcn_mfma_f32_16x16x32_bf16(af[mi], bg[g], acc[mi][g], 0, 0, 0);
      __syncthreads();
    }

    // pointwise LSTM
    const int fq = (lane >> 4) * 4;
    const int hcol = n0 + fr;
    #pragma unroll
    for (int mi = 0; mi < 2; ++mi) {
      #pragma unroll
      for (int j = 0; j < 4; ++j) {
        int r = wid * 32 + mi * 16 + fq + j;
        float gi = acc[mi][0][j] + (float)preG[(size_t)r * 2048 + hcol];
        float gf = acc[mi][1][j] + (float)preG[(size_t)r * 2048 + 512 + hcol];
        float gg = acc[mi][2][j] + (float)preG[(size_t)r * 2048 + 1024 + hcol];
        float go = acc[mi][3][j] + (float)preG[(size_t)r * 2048 + 1536 + hcol];
        float cold = c_state[(size_t)r * 512 + hcol];
        float cn = sigf(gf) * cold + sigf(gi) * tanhf(gg);
        float hn = sigf(go) * tanhf(cn);
        c_state[(size_t)r * 512 + hcol] = cn;
        h_out[(size_t)r * 512 + hcol] = (bf16)hn;
        if (is_enc) {
          int len = kw_lens[r];
          hsEnc_t[(size_t)r * 512 + hcol] = (t < len) ? (bf16)hn : (bf16)0.f;
          if (t == len - 1) {
            h0b[(size_t)r * 512 + hcol] = (bf16)hn;
            c0f[(size_t)r * 512 + hcol] = cn;
          }
        }
      }
    }
  } else {
    // ------------------- attention for step t-1 -------------------
    if (!do_attn) return;
    const int b = blockIdx.x - 32;
    // scores: wave w does l = w and l = w+4
    #pragma unroll
    for (int li = 0; li < 2; ++li) {
      int l = wid + li * 4;
      float p = 0.f;
      #pragma unroll
      for (int e = 0; e < 8; ++e) {
        int h = lane + 64 * e;
        p += (float)h_in[(size_t)b * 512 + h] * (float)hsEnc_all[((size_t)(l * 128 + b) << 9) + h];
      }
      #pragma unroll
      for (int off = 32; off > 0; off >>= 1) p += __shfl_xor(p, off);
      if (lane == 0) sc[l] = p;
    }
    __syncthreads();
    const int len = kw_lens[b];
    float m = -1e30f;
    for (int l = 0; l < len; ++l) m = fmaxf(m, sc[l]);
    float w8[8]; float den = 0.f;
    #pragma unroll
    for (int l = 0; l < 8; ++l) { w8[l] = (l < len) ? expf(sc[l] - m) : 0.f; den += w8[l]; }
    const float inv = 1.f / den;
    #pragma unroll
    for (int rep = 0; rep < 2; ++rep) {
      int h = tid + rep * 256;
      float ctx = 0.f;
      #pragma unroll
      for (int l = 0; l < 8; ++l)
        ctx += w8[l] * inv * (float)hsEnc_all[((size_t)(l * 128 + b) << 9) + h];
      Hcat_prev[(size_t)b * 1024 + 512 + h] = (bf16)ctx;
      Hcat_prev[(size_t)b * 1024 + h] = h_in[(size_t)b * 512 + h];
    }
  }
}

// ---------------------------------------------------------------------------
extern "C" void kernel_launch(void* const* d_in, const int* in_sizes, int n_in,
                              void* d_out, int out_size, void* d_ws, size_t ws_size,
                              hipStream_t stream)
{
  const int* kws  = (const int*)d_in[0];
  const int* poem = (const int*)d_in[1];
  const int* kwl  = (const int*)d_in[2];
  const float* emb  = (const float*)d_in[3];
  const float* eWih = (const float*)d_in[4];
  const float* eWhh = (const float*)d_in[5];
  const float* eb   = (const float*)d_in[6];
  const float* dWih = (const float*)d_in[7];
  const float* dWhh = (const float*)d_in[8];
  const float* db   = (const float*)d_in[9];
  const float* outW = (const float*)d_in[10];
  const float* outb = (const float*)d_in[11];
  float* out = (float*)d_out;

  char* base = (char*)d_ws;
  size_t o = 0;
  auto take = [&](size_t bytes) -> char* {
    char* r = base + o;
    o += (bytes + 255) & ~(size_t)255;
    return r;
  };
  bf16* WihE  = (bf16*)take(2048 * 512 * 2);
  bf16* WhhE  = (bf16*)take(2048 * 512 * 2);
  bf16* WihD  = (bf16*)take(2048 * 512 * 2);
  bf16* WhhD  = (bf16*)take(2048 * 512 * 2);
  bf16* outWb = (bf16*)take((size_t)10000 * 1024 * 2);
  bf16* Xenc  = (bf16*)take(1024 * 512 * 2);
  bf16* Xdec  = (bf16*)take((size_t)6144 * 512 * 2);
  bf16* preEnc = (bf16*)take((size_t)1024 * 2048 * 2);
  bf16* preDec = (bf16*)take((size_t)6144 * 2048 * 2);
  bf16* hsEnc  = (bf16*)take((size_t)8 * 128 * 512 * 2);
  bf16* h0b    = (bf16*)take(128 * 512 * 2);
  float* c0f   = (float*)take(128 * 512 * 4);
  float* cE    = (float*)take(128 * 512 * 4);
  bf16* hbE0   = (bf16*)take(128 * 512 * 2);
  bf16* hbE1   = (bf16*)take(128 * 512 * 2);
  bf16* hbD0   = (bf16*)take(128 * 512 * 2);
  bf16* hbD1   = (bf16*)take(128 * 512 * 2);
  bf16* Hcat   = (bf16*)take((size_t)6144 * 1024 * 2);

  prep_kernel<<<4096, 256, 0, stream>>>(kws, poem, emb, eWih, eWhh, dWih, dWhh, outW,
                                        WihE, WhhE, WihD, WhhD, outWb, Xenc, Xdec, cE, hbE0);

  // pre-gates: x @ Wih^T + b  (bias folded here)
  gemm_nt_kernel<true, false><<<dim3(16, 8), 256, 0, stream>>>(Xenc, WihE, eb, preEnc, 1024, 2048, 512);
  gemm_nt_kernel<true, false><<<dim3(16, 48), 256, 0, stream>>>(Xdec, WihD, db, preDec, 6144, 2048, 512);

  // encoder: 8 steps
  bf16* hbE[2] = {hbE0, hbE1};
  for (int t = 0; t < 8; ++t) {
    const bf16* hin = hbE[t & 1];
    bf16* hout = hbE[(t + 1) & 1];
    step_kernel<<<32, 256, 0, stream>>>(hin, hout, cE,
        preEnc + (size_t)t * 128 * 2048, WhhE,
        hsEnc + (size_t)t * 128 * 512, h0b, c0f, kwl, t, 1,
        nullptr, nullptr, 1, 0);
  }

  // decoder: 48 steps + trailing attention-only launch (t == 48)
  bf16* hbD[2] = {hbD0, hbD1};
  for (int t = 0; t <= 48; ++t) {
    const bf16* hin = (t == 0) ? h0b : hbD[t & 1];
    bf16* hout = hbD[(t + 1) & 1];
    int dg = (t < 48) ? 1 : 0;
    int da = (t > 0) ? 1 : 0;
    step_kernel<<<160, 256, 0, stream>>>(hin, hout, c0f,
        preDec + (size_t)(dg ? t : 0) * 128 * 2048, WhhD,
        nullptr, nullptr, nullptr, kwl, t, 0,
        hsEnc, Hcat + (size_t)(da ? t - 1 : 0) * 128 * 1024, dg, da);
  }

  // final projection: [h|ctx] @ out_W^T + out_b, scattered to [B,T,V]
  gemm_nt_kernel<false, true><<<dim3(79, 48), 256, 0, stream>>>(Hcat, outWb, outb, out, 6144, 10000, 1024);
}

// Round 2
// 1029.253 us; speedup vs baseline: 1.1007x; 1.1007x over previous
//
#include <hip/hip_runtime.h>
#include <hip/hip_bf16.h>

typedef __bf16 bf16;
typedef __attribute__((ext_vector_type(8))) __bf16 bf16x8;
typedef __attribute__((ext_vector_type(4))) __bf16 bf16x4;
typedef __attribute__((ext_vector_type(4))) float f32x4;

#define B_ 128
#define L_ 8
#define T_ 48
#define V_ 10000
#define NBLK_REC 32

__device__ __forceinline__ float sigf(float x) { return 1.f / (1.f + expf(-x)); }

__device__ __forceinline__ void gl_lds16(const bf16* g, bf16* l) {
  __builtin_amdgcn_global_load_lds(
      (const __attribute__((address_space(1))) unsigned int*)g,
      (__attribute__((address_space(3))) unsigned int*)l, 16, 0, 0);
}

// ---------------------------------------------------------------------------
// Prep: cast weights f32->bf16 (outW padded to 10112 rows), gather embeddings,
// zero encoder state + barrier counters.
// ---------------------------------------------------------------------------
__global__ void prep_kernel(
    const int* __restrict__ kws, const int* __restrict__ poem,
    const float* __restrict__ emb,
    const float* __restrict__ eWih, const float* __restrict__ eWhh,
    const float* __restrict__ dWih, const float* __restrict__ dWhh,
    const float* __restrict__ outW,
    bf16* __restrict__ WihE, bf16* __restrict__ WhhE,
    bf16* __restrict__ WihD, bf16* __restrict__ WhhD,
    bf16* __restrict__ outWb,
    bf16* __restrict__ Xenc, bf16* __restrict__ Xdec,
    float* __restrict__ cE, bf16* __restrict__ hbE0,
    unsigned* __restrict__ bar)
{
  if (blockIdx.x == 0 && threadIdx.x == 0) { bar[0] = 0u; bar[1] = 0u; }
  const long SW = 1048576;       // 2048*512
  const long SOWP = 10354688;    // 10112*1024 (padded)
  const long SXE = 524288;       // 1024*512
  const long SXD = 3145728;      // 6144*512
  const long SZ = 65536;         // 128*512
  const long total = 4 * SW + SOWP + SXE + SXD + SZ;
  for (long i = blockIdx.x * (long)blockDim.x + threadIdx.x; i < total;
       i += (long)gridDim.x * blockDim.x) {
    long j = i;
    if (j < SW) { WihE[j] = (bf16)eWih[j]; continue; } j -= SW;
    if (j < SW) { WhhE[j] = (bf16)eWhh[j]; continue; } j -= SW;
    if (j < SW) { WihD[j] = (bf16)dWih[j]; continue; } j -= SW;
    if (j < SW) { WhhD[j] = (bf16)dWhh[j]; continue; } j -= SW;
    if (j < SOWP) {
      long r = j >> 10;
      outWb[j] = (r < 10000) ? (bf16)outW[j] : (bf16)0.f;
      continue;
    } j -= SOWP;
    if (j < SXE) {
      int e = (int)(j & 511); int b = (int)((j >> 9) & 127); int l = (int)(j >> 16);
      int tok = kws[b * L_ + l];
      Xenc[j] = (bf16)emb[(long)tok * 512 + e];
      continue;
    } j -= SXE;
    if (j < SXD) {
      int e = (int)(j & 511); int b = (int)((j >> 9) & 127); int t = (int)(j >> 16);
      int tok = poem[b * T_ + t];
      Xdec[j] = (bf16)emb[(long)tok * 512 + e];
      continue;
    } j -= SXD;
    cE[j] = 0.f; hbE0[j] = (bf16)0.f;
  }
}

// ---------------------------------------------------------------------------
// m97-structure NT GEMM: C[M,N] = A[M,K]*B[N,K]^T + bias.
// 128x128 tile, BK=32, global_load_lds width-16 staging, linear 8KB LDS tiles.
// MODE 2: scatter f32 to out[b][t][V] (row = t*128+b).
// MODE 3: bf16 transposed pre-gate store [t][2048][128].
// ---------------------------------------------------------------------------
template<int MODE>
__global__ __launch_bounds__(256) void gemm2_kernel(
    const bf16* __restrict__ A, const bf16* __restrict__ Bm,
    const float* __restrict__ bias, void* __restrict__ outp,
    int M, int N, int K, int MT)
{
  __shared__ bf16 As[128 * 32];
  __shared__ bf16 Bs[128 * 32];
  const int tid = threadIdx.x, lane = tid & 63, wid = tid >> 6;
  const int nwg = gridDim.x;
  int bid = blockIdx.x;
  int swz = ((nwg & 7) == 0) ? ((bid & 7) * (nwg >> 3) + (bid >> 3)) : bid;
  const int tm = swz % MT, tn = swz / MT;
  const int m0 = tm * 128, n0 = tn * 128;
  const int wm = (wid >> 1) * 64, wn = (wid & 1) * 64;
  const int fr = lane & 15, ku = lane >> 4;

  f32x4 acc[4][4];
  #pragma unroll
  for (int mi = 0; mi < 4; ++mi)
    #pragma unroll
    for (int ni = 0; ni < 4; ++ni) {
      acc[mi][ni][0] = 0.f; acc[mi][ni][1] = 0.f;
      acc[mi][ni][2] = 0.f; acc[mi][ni][3] = 0.f;
    }

  for (int kt = 0; kt < K; kt += 32) {
    #pragma unroll
    for (int j = 0; j < 2; ++j) {
      int i0 = j * 256 + wid * 64;
      int i = i0 + lane;
      int r = i >> 2, ub = i & 3;
      gl_lds16(A + (size_t)(m0 + r) * K + kt + ub * 8, As + (size_t)i0 * 8);
      gl_lds16(Bm + (size_t)(n0 + r) * K + kt + ub * 8, Bs + (size_t)i0 * 8);
    }
    __syncthreads();
    bf16x8 af[4], bfr[4];
    #pragma unroll
    for (int mi = 0; mi < 4; ++mi)
      af[mi] = *(const bf16x8*)(As + (size_t)(wm + mi * 16 + fr) * 32 + ku * 8);
    #pragma unroll
    for (int ni = 0; ni < 4; ++ni)
      bfr[ni] = *(const bf16x8*)(Bs + (size_t)(wn + ni * 16 + fr) * 32 + ku * 8);
    #pragma unroll
    for (int mi = 0; mi < 4; ++mi)
      #pragma unroll
      for (int ni = 0; ni < 4; ++ni)
        acc[mi][ni] = __builtin_amdgcn_mfma_f32_16x16x32_bf16(af[mi], bfr[ni], acc[mi][ni], 0, 0, 0);
    __syncthreads();
  }

  const int fq = (lane >> 4) * 4;
  #pragma unroll
  for (int mi = 0; mi < 4; ++mi) {
    #pragma unroll
    for (int ni = 0; ni < 4; ++ni) {
      #pragma unroll
      for (int j = 0; j < 4; ++j) {
        int r = m0 + wm + mi * 16 + fq + j;
        int cix = n0 + wn + ni * 16 + fr;
        if (cix < N) {
          float v = acc[mi][ni][j] + bias[cix];
          if (MODE == 2) {
            int b = r & 127, t = r >> 7;
            ((float*)outp)[(size_t)b * (T_ * V_) + (size_t)t * V_ + cix] = v;
          } else {
            ((bf16*)outp)[((size_t)(r >> 7) * 2048 + cix) * 128 + (r & 127)] = (bf16)v;
          }
        }
      }
    }
  }
}

// ---------------------------------------------------------------------------
// Device-scope grid barrier (32 co-resident blocks).
// ---------------------------------------------------------------------------
__device__ __forceinline__ void gridbar(unsigned* bar) {
  __syncthreads();
  if (threadIdx.x == 0) {
    unsigned g = __hip_atomic_load(bar + 1, __ATOMIC_RELAXED, __HIP_MEMORY_SCOPE_AGENT);
    unsigned a = __hip_atomic_fetch_add(bar, 1u, __ATOMIC_ACQ_REL, __HIP_MEMORY_SCOPE_AGENT);
    if (a == NBLK_REC - 1) {
      __hip_atomic_store(bar, 0u, __ATOMIC_RELAXED, __HIP_MEMORY_SCOPE_AGENT);
      __hip_atomic_store(bar + 1, g + 1u, __ATOMIC_RELEASE, __HIP_MEMORY_SCOPE_AGENT);
    } else {
      while (__hip_atomic_load(bar + 1, __ATOMIC_ACQUIRE, __HIP_MEMORY_SCOPE_AGENT) == g) {
        __builtin_amdgcn_s_sleep(2);
      }
    }
  }
  __syncthreads();
}

// ---------------------------------------------------------------------------
// Persistent recurrent kernel: encoder 8 steps + decoder 48 steps + attention.
// 32 blocks x 256 threads. Block b owns 16 H-cols (x4 gates) of the step GEMM
// and batches 4b..4b+3 of attention. Whh slice persistent in LDS (swizzled).
// ---------------------------------------------------------------------------
__global__ __launch_bounds__(256) void recurrent_kernel(
    const bf16* __restrict__ preEncT, const bf16* __restrict__ preDecT,
    const bf16* __restrict__ WhhE, const bf16* __restrict__ WhhD,
    const int* __restrict__ kwl,
    float* __restrict__ cE, float* __restrict__ c0f,
    bf16* __restrict__ hbE0, bf16* __restrict__ hbE1,
    bf16* __restrict__ hbD0, bf16* __restrict__ hbD1,
    bf16* __restrict__ h0b, bf16* __restrict__ hsEnc,
    bf16* __restrict__ Hcat, unsigned* __restrict__ bar)
{
  __shared__ bf16 Bs[64 * 512];    // persistent Whh slice, XOR-swizzled
  __shared__ bf16 As[128 * 256];   // h chunk (256 of 512 K-cols), XOR-swizzled
  const int tid = threadIdx.x, lane = tid & 63, wid = tid >> 6;
  const int blk = blockIdx.x;
  const int n0 = blk * 16;
  const int fr = lane & 15, fq = (lane >> 4) * 4, ku = lane >> 4;
  const int axor = fr & 7;

  auto loadB = [&](const bf16* W) {
    #pragma unroll
    for (int j = 0; j < 16; ++j) {
      int i = j * 256 + tid;
      int r = i >> 6, u = i & 63;
      int p = u ^ (r & 7);
      bf16x8 v = *(const bf16x8*)(W + (size_t)((r >> 4) * 512 + n0 + (r & 15)) * 512 + u * 8);
      *(bf16x8*)(Bs + (size_t)r * 512 + p * 8) = v;
    }
  };

  auto stageA = [&](const bf16* h, int ch) {
    #pragma unroll
    for (int j = 0; j < 16; ++j) {
      int i0 = j * 256 + wid * 64;
      int i = i0 + lane;
      int r = i >> 5, up = i & 31;
      int us = up ^ (r & 7);
      gl_lds16(h + (size_t)r * 512 + ch * 256 + us * 8, As + (size_t)i0 * 8);
    }
  };

  auto do_step = [&](const bf16* h_in, bf16* h_out, float* cst, const bf16* preT,
                     int is_enc, int t, bf16* hsEnc_t) {
    f32x4 acc[2][4];
    #pragma unroll
    for (int mi = 0; mi < 2; ++mi)
      #pragma unroll
      for (int g = 0; g < 4; ++g) {
        acc[mi][g][0] = 0.f; acc[mi][g][1] = 0.f;
        acc[mi][g][2] = 0.f; acc[mi][g][3] = 0.f;
      }

    #pragma unroll
    for (int ch = 0; ch < 2; ++ch) {
      stageA(h_in, ch);
      __syncthreads();
      #pragma unroll
      for (int kt = 0; kt < 8; ++kt) {
        int cA = (kt * 4 + ku) ^ axor;
        int cB = ((ch * 8 + kt) * 4 + ku) ^ axor;
        bf16x8 af[2];
        #pragma unroll
        for (int mi = 0; mi < 2; ++mi) {
          int r = wid * 32 + mi * 16 + fr;
          af[mi] = *(const bf16x8*)(As + (size_t)r * 256 + cA * 8);
        }
        #pragma unroll
        for (int g = 0; g < 4; ++g) {
          int rb = g * 16 + fr;
          bf16x8 bv = *(const bf16x8*)(Bs + (size_t)rb * 512 + cB * 8);
          #pragma unroll
          for (int mi = 0; mi < 2; ++mi)
            acc[mi][g] = __builtin_amdgcn_mfma_f32_16x16x32_bf16(af[mi], bv, acc[mi][g], 0, 0, 0);
        }
      }
      __syncthreads();
    }

    // pointwise LSTM (block-private columns)
    #pragma unroll
    for (int mi = 0; mi < 2; ++mi) {
      int rbase = wid * 32 + mi * 16 + fq;
      int hcol = n0 + fr;
      bf16x4 gv[4];
      #pragma unroll
      for (int g = 0; g < 4; ++g)
        gv[g] = *(const bf16x4*)(preT + (size_t)(g * 512 + hcol) * 128 + rbase);
      #pragma unroll
      for (int j = 0; j < 4; ++j) {
        int r = rbase + j;
        float gi = acc[mi][0][j] + (float)gv[0][j];
        float gf = acc[mi][1][j] + (float)gv[1][j];
        float gg = acc[mi][2][j] + (float)gv[2][j];
        float go = acc[mi][3][j] + (float)gv[3][j];
        float cold = cst[(size_t)r * 512 + hcol];
        float cn = sigf(gf) * cold + sigf(gi) * tanhf(gg);
        float hn = sigf(go) * tanhf(cn);
        cst[(size_t)r * 512 + hcol] = cn;
        h_out[(size_t)r * 512 + hcol] = (bf16)hn;
        if (is_enc) {
          int len = kwl[r];
          hsEnc_t[(size_t)r * 512 + hcol] = (t < len) ? (bf16)hn : (bf16)0.f;
          if (t == len - 1) {
            h0b[(size_t)r * 512 + hcol] = (bf16)hn;
            c0f[(size_t)r * 512 + hcol] = cn;
          }
        }
      }
    }
  };

  auto attention = [&](const bf16* h, int tprev) {
    int b = blk * 4 + wid;
    float hreg[8];
    #pragma unroll
    for (int e = 0; e < 8; ++e) hreg[e] = (float)h[(size_t)b * 512 + lane + 64 * e];
    float sc[8];
    #pragma unroll
    for (int l = 0; l < 8; ++l) {
      float p = 0.f;
      #pragma unroll
      for (int e = 0; e < 8; ++e)
        p += hreg[e] * (float)hsEnc[((size_t)(l * 128 + b)) * 512 + lane + 64 * e];
      #pragma unroll
      for (int off = 32; off; off >>= 1) p += __shfl_xor(p, off);
      sc[l] = p;
    }
    int len = kwl[b];
    float m = -1e30f;
    #pragma unroll
    for (int l = 0; l < 8; ++l) m = fmaxf(m, (l < len) ? sc[l] : -1e30f);
    float wgt[8]; float den = 0.f;
    #pragma unroll
    for (int l = 0; l < 8; ++l) { wgt[l] = (l < len) ? expf(sc[l] - m) : 0.f; den += wgt[l]; }
    float inv = 1.f / den;
    bf16* dst = Hcat + ((size_t)tprev * 128 + b) * 1024;
    #pragma unroll
    for (int e = 0; e < 8; ++e) {
      float ctx = 0.f;
      #pragma unroll
      for (int l = 0; l < 8; ++l)
        ctx += wgt[l] * (float)hsEnc[((size_t)(l * 128 + b)) * 512 + lane + 64 * e];
      dst[512 + lane + 64 * e] = (bf16)(ctx * inv);
      dst[lane + 64 * e] = (bf16)hreg[e];
    }
  };

  // ---------------- encoder ----------------
  loadB(WhhE);
  __syncthreads();
  bf16* hbE[2] = {hbE0, hbE1};
  for (int t = 0; t < 8; ++t) {
    do_step(hbE[t & 1], hbE[(t + 1) & 1], cE, preEncT + (size_t)t * 2048 * 128,
            1, t, hsEnc + (size_t)t * 128 * 512);
    gridbar(bar);
  }
  __syncthreads();
  loadB(WhhD);
  __syncthreads();
  // ---------------- decoder ----------------
  bf16* hbD[2] = {hbD0, hbD1};
  for (int t = 0; t < 48; ++t) {
    const bf16* hin = (t == 0) ? (const bf16*)h0b : (const bf16*)hbD[t & 1];
    do_step(hin, hbD[(t + 1) & 1], c0f, preDecT + (size_t)t * 2048 * 128, 0, t, nullptr);
    if (t >= 1) attention(hin, t - 1);
    gridbar(bar);
  }
  attention(hbD[0], 47);
}

// ---------------------------------------------------------------------------
extern "C" void kernel_launch(void* const* d_in, const int* in_sizes, int n_in,
                              void* d_out, int out_size, void* d_ws, size_t ws_size,
                              hipStream_t stream)
{
  const int* kws  = (const int*)d_in[0];
  const int* poem = (const int*)d_in[1];
  const int* kwl  = (const int*)d_in[2];
  const float* emb  = (const float*)d_in[3];
  const float* eWih = (const float*)d_in[4];
  const float* eWhh = (const float*)d_in[5];
  const float* eb   = (const float*)d_in[6];
  const float* dWih = (const float*)d_in[7];
  const float* dWhh = (const float*)d_in[8];
  const float* db   = (const float*)d_in[9];
  const float* outW = (const float*)d_in[10];
  const float* outb = (const float*)d_in[11];
  float* out = (float*)d_out;

  char* base = (char*)d_ws;
  size_t o = 0;
  auto take = [&](size_t bytes) -> char* {
    char* r = base + o;
    o += (bytes + 255) & ~(size_t)255;
    return r;
  };
  bf16* WihE  = (bf16*)take(2048 * 512 * 2);
  bf16* WhhE  = (bf16*)take(2048 * 512 * 2);
  bf16* WihD  = (bf16*)take(2048 * 512 * 2);
  bf16* WhhD  = (bf16*)take(2048 * 512 * 2);
  bf16* outWb = (bf16*)take((size_t)10112 * 1024 * 2);   // padded to 79*128 rows
  bf16* Xenc  = (bf16*)take(1024 * 512 * 2);
  bf16* Xdec  = (bf16*)take((size_t)6144 * 512 * 2);
  bf16* preEncT = (bf16*)take((size_t)8 * 2048 * 128 * 2);
  bf16* preDecT = (bf16*)take((size_t)48 * 2048 * 128 * 2);
  bf16* hsEnc  = (bf16*)take((size_t)8 * 128 * 512 * 2);
  bf16* h0b    = (bf16*)take(128 * 512 * 2);
  float* c0f   = (float*)take(128 * 512 * 4);
  float* cE    = (float*)take(128 * 512 * 4);
  bf16* hbE0   = (bf16*)take(128 * 512 * 2);
  bf16* hbE1   = (bf16*)take(128 * 512 * 2);
  bf16* hbD0   = (bf16*)take(128 * 512 * 2);
  bf16* hbD1   = (bf16*)take(128 * 512 * 2);
  bf16* Hcat   = (bf16*)take((size_t)6144 * 1024 * 2);
  unsigned* bar = (unsigned*)take(256);

  prep_kernel<<<4096, 256, 0, stream>>>(kws, poem, emb, eWih, eWhh, dWih, dWhh, outW,
                                        WihE, WhhE, WihD, WhhD, outWb, Xenc, Xdec,
                                        cE, hbE0, bar);

  // pre-gates (bias folded), stored transposed [t][2048][128]
  gemm2_kernel<3><<<128, 256, 0, stream>>>(Xenc, WihE, eb, preEncT, 1024, 2048, 512, 8);
  gemm2_kernel<3><<<768, 256, 0, stream>>>(Xdec, WihD, db, preDecT, 6144, 2048, 512, 48);

  // persistent encoder + decoder + attention
  recurrent_kernel<<<NBLK_REC, 256, 0, stream>>>(preEncT, preDecT, WhhE, WhhD, kwl,
                                                 cE, c0f, hbE0, hbE1, hbD0, hbD1,
                                                 h0b, hsEnc, Hcat, bar);

  // final projection: [h|ctx] @ out_W^T + out_b, scattered to [B,T,V]
  gemm2_kernel<2><<<3792, 256, 0, stream>>>(Hcat, outWb, outb, out, 6144, 10000, 1024, 48);
}

// Round 3
// 892.991 us; speedup vs baseline: 1.2687x; 1.1526x over previous
//
#include <hip/hip_runtime.h>
#include <hip/hip_bf16.h>

typedef __bf16 bf16;
typedef __attribute__((ext_vector_type(8))) __bf16 bf16x8;
typedef __attribute__((ext_vector_type(4))) __bf16 bf16x4;
typedef __attribute__((ext_vector_type(4))) float f32x4;

#define B_ 128
#define L_ 8
#define T_ 48
#define V_ 10000
#define NBLK_REC 32

__device__ __forceinline__ float sigf(float x) { return 1.f / (1.f + expf(-x)); }

__device__ __forceinline__ void gl_lds16(const bf16* g, bf16* l) {
  __builtin_amdgcn_global_load_lds(
      (const __attribute__((address_space(1))) unsigned int*)g,
      (__attribute__((address_space(3))) unsigned int*)l, 16, 0, 0);
}

__device__ __forceinline__ unsigned long long aload64(const void* p) {
  return __hip_atomic_load((unsigned long long*)p, __ATOMIC_RELAXED, __HIP_MEMORY_SCOPE_AGENT);
}
__device__ __forceinline__ unsigned aload32(const void* p) {
  return __hip_atomic_load((unsigned*)p, __ATOMIC_RELAXED, __HIP_MEMORY_SCOPE_AGENT);
}
__device__ __forceinline__ void astore64(void* p, unsigned long long v) {
  __hip_atomic_store((unsigned long long*)p, v, __ATOMIC_RELAXED, __HIP_MEMORY_SCOPE_AGENT);
}
__device__ __forceinline__ float bflo(unsigned u) { return __uint_as_float(u << 16); }
__device__ __forceinline__ float bfhi(unsigned u) { return __uint_as_float(u & 0xffff0000u); }
__device__ __forceinline__ unsigned packbf(float lo, float hi) {
  bf16 a = (bf16)lo, b = (bf16)hi;
  unsigned short ua = __builtin_bit_cast(unsigned short, a);
  unsigned short ub = __builtin_bit_cast(unsigned short, b);
  return (unsigned)ua | ((unsigned)ub << 16);
}

// step-counter barrier helpers (relaxed, no cache flush)
__device__ __forceinline__ void arrive(unsigned* c) {
  asm volatile("s_waitcnt vmcnt(0)" ::: "memory");
  __syncthreads();
  if (threadIdx.x == 0)
    __hip_atomic_fetch_add(c, 1u, __ATOMIC_RELAXED, __HIP_MEMORY_SCOPE_AGENT);
}
__device__ __forceinline__ void waitall(unsigned* c) {
  if (threadIdx.x == 0) {
    while (__hip_atomic_load(c, __ATOMIC_RELAXED, __HIP_MEMORY_SCOPE_AGENT) < NBLK_REC)
      __builtin_amdgcn_s_sleep(1);
  }
  __syncthreads();
}

// ---------------------------------------------------------------------------
// Prep: cast weights f32->bf16 (outW padded to 10112 rows), gather embeddings,
// zero step counters.
// ---------------------------------------------------------------------------
__global__ void prep_kernel(
    const int* __restrict__ kws, const int* __restrict__ poem,
    const float* __restrict__ emb,
    const float* __restrict__ eWih, const float* __restrict__ eWhh,
    const float* __restrict__ dWih, const float* __restrict__ dWhh,
    const float* __restrict__ outW,
    bf16* __restrict__ WihE, bf16* __restrict__ WhhE,
    bf16* __restrict__ WihD, bf16* __restrict__ WhhD,
    bf16* __restrict__ outWb,
    bf16* __restrict__ Xenc, bf16* __restrict__ Xdec,
    unsigned* __restrict__ cnt)
{
  if (blockIdx.x == 0 && threadIdx.x < 64) cnt[threadIdx.x] = 0u;
  const long SW = 1048576;       // 2048*512
  const long SOWP = 10354688;    // 10112*1024 (padded)
  const long SXE = 524288;       // 1024*512
  const long SXD = 3145728;      // 6144*512
  const long total = 4 * SW + SOWP + SXE + SXD;
  for (long i = blockIdx.x * (long)blockDim.x + threadIdx.x; i < total;
       i += (long)gridDim.x * blockDim.x) {
    long j = i;
    if (j < SW) { WihE[j] = (bf16)eWih[j]; continue; } j -= SW;
    if (j < SW) { WhhE[j] = (bf16)eWhh[j]; continue; } j -= SW;
    if (j < SW) { WihD[j] = (bf16)dWih[j]; continue; } j -= SW;
    if (j < SW) { WhhD[j] = (bf16)dWhh[j]; continue; } j -= SW;
    if (j < SOWP) {
      long r = j >> 10;
      outWb[j] = (r < 10000) ? (bf16)outW[j] : (bf16)0.f;
      continue;
    } j -= SOWP;
    if (j < SXE) {
      int e = (int)(j & 511); int b = (int)((j >> 9) & 127); int l = (int)(j >> 16);
      int tok = kws[b * L_ + l];
      Xenc[j] = (bf16)emb[(long)tok * 512 + e];
      continue;
    } j -= SXE;
    {
      int e = (int)(j & 511); int b = (int)((j >> 9) & 127); int t = (int)(j >> 16);
      int tok = poem[b * T_ + t];
      Xdec[j] = (bf16)emb[(long)tok * 512 + e];
    }
  }
}

// ---------------------------------------------------------------------------
// m97-structure NT GEMM: C[M,N] = A[M,K]*B[N,K]^T + bias.
// MODE 2: scatter f32 to out[b][t][V] (row = t*128+b).
// MODE 3: bf16 transposed pre-gate store [t][2048][128].
// ---------------------------------------------------------------------------
template<int MODE>
__global__ __launch_bounds__(256) void gemm2_kernel(
    const bf16* __restrict__ A, const bf16* __restrict__ Bm,
    const float* __restrict__ bias, void* __restrict__ outp,
    int M, int N, int K, int MT)
{
  __shared__ bf16 As[128 * 32];
  __shared__ bf16 Bs[128 * 32];
  const int tid = threadIdx.x, lane = tid & 63, wid = tid >> 6;
  const int nwg = gridDim.x;
  int bid = blockIdx.x;
  int swz = ((nwg & 7) == 0) ? ((bid & 7) * (nwg >> 3) + (bid >> 3)) : bid;
  const int tm = swz % MT, tn = swz / MT;
  const int m0 = tm * 128, n0 = tn * 128;
  const int wm = (wid >> 1) * 64, wn = (wid & 1) * 64;
  const int fr = lane & 15, ku = lane >> 4;

  f32x4 acc[4][4];
  #pragma unroll
  for (int mi = 0; mi < 4; ++mi)
    #pragma unroll
    for (int ni = 0; ni < 4; ++ni) {
      acc[mi][ni][0] = 0.f; acc[mi][ni][1] = 0.f;
      acc[mi][ni][2] = 0.f; acc[mi][ni][3] = 0.f;
    }

  for (int kt = 0; kt < K; kt += 32) {
    #pragma unroll
    for (int j = 0; j < 2; ++j) {
      int i0 = j * 256 + wid * 64;
      int i = i0 + lane;
      int r = i >> 2, ub = i & 3;
      gl_lds16(A + (size_t)(m0 + r) * K + kt + ub * 8, As + (size_t)i0 * 8);
      gl_lds16(Bm + (size_t)(n0 + r) * K + kt + ub * 8, Bs + (size_t)i0 * 8);
    }
    __syncthreads();
    bf16x8 af[4], bfr[4];
    #pragma unroll
    for (int mi = 0; mi < 4; ++mi)
      af[mi] = *(const bf16x8*)(As + (size_t)(wm + mi * 16 + fr) * 32 + ku * 8);
    #pragma unroll
    for (int ni = 0; ni < 4; ++ni)
      bfr[ni] = *(const bf16x8*)(Bs + (size_t)(wn + ni * 16 + fr) * 32 + ku * 8);
    #pragma unroll
    for (int mi = 0; mi < 4; ++mi)
      #pragma unroll
      for (int ni = 0; ni < 4; ++ni)
        acc[mi][ni] = __builtin_amdgcn_mfma_f32_16x16x32_bf16(af[mi], bfr[ni], acc[mi][ni], 0, 0, 0);
    __syncthreads();
  }

  const int fq = (lane >> 4) * 4;
  #pragma unroll
  for (int mi = 0; mi < 4; ++mi) {
    #pragma unroll
    for (int ni = 0; ni < 4; ++ni) {
      #pragma unroll
      for (int j = 0; j < 4; ++j) {
        int r = m0 + wm + mi * 16 + fq + j;
        int cix = n0 + wn + ni * 16 + fr;
        if (cix < N) {
          float v = acc[mi][ni][j] + bias[cix];
          if (MODE == 2) {
            int b = r & 127, t = r >> 7;
            ((float*)outp)[(size_t)b * (T_ * V_) + (size_t)t * V_ + cix] = v;
          } else {
            ((bf16*)outp)[((size_t)(r >> 7) * 2048 + cix) * 128 + (r & 127)] = (bf16)v;
          }
        }
      }
    }
  }
}

// ---------------------------------------------------------------------------
// Persistent recurrent kernel, coherence-safe without cache flushes:
// h/hsEnc/h0b exchanged via relaxed agent-scope atomics (write-through /
// L2-bypass); c-state in registers; per-step arrive counters.
// ---------------------------------------------------------------------------
__global__ __launch_bounds__(256, 1) void recurrent_kernel(
    const bf16* __restrict__ preEncT, const bf16* __restrict__ preDecT,
    const bf16* __restrict__ WhhE, const bf16* __restrict__ WhhD,
    const int* __restrict__ kwl,
    bf16* __restrict__ hS,      // 56 slots of 128*512 (enc t -> t, dec t -> 8+t)
    bf16* __restrict__ h0b,
    bf16* __restrict__ hsEnc,   // [8][128][512]
    bf16* __restrict__ Hcat,    // [48][128][1024]
    unsigned* __restrict__ cnt)
{
  __shared__ bf16 Bs[64 * 512];    // persistent Whh slice, XOR-swizzled
  __shared__ bf16 As[128 * 256];   // h half (256 K-cols), XOR-swizzled; also bounce buf
  const int tid = threadIdx.x, lane = tid & 63, wid = tid >> 6;
  const int blk = blockIdx.x, n0 = blk * 16;
  const int fr = lane & 15, fq = (lane >> 4) * 4, ku = lane >> 4;
  const int axor = fr & 7;
  const int arow0 = wid * 32 + fr, arow1 = wid * 32 + 16 + fr;
  const int row0 = wid * 32 + fq, row1 = wid * 32 + 16 + fq;
  const int brow = tid >> 1, bhalf = tid & 1;
  const int blen = kwl[brow];
  const int batt = blk * 4 + wid;
  const int lenb = kwl[batt];
  int lenr[2][4];
  #pragma unroll
  for (int j = 0; j < 4; ++j) { lenr[0][j] = kwl[row0 + j]; lenr[1][j] = kwl[row1 + j]; }

  auto loadB = [&](const bf16* W) {
    #pragma unroll
    for (int j = 0; j < 16; ++j) {
      int i = j * 256 + tid;
      int r = i >> 6, u = i & 63;
      int p = u ^ (r & 7);
      bf16x8 v = *(const bf16x8*)(W + (size_t)((r >> 4) * 512 + n0 + (r & 15)) * 512 + u * 8);
      *(bf16x8*)(Bs + (size_t)r * 512 + p * 8) = v;
    }
  };

  f32x4 acc[2][4];
  auto zacc = [&]() {
    #pragma unroll
    for (int mi = 0; mi < 2; ++mi)
      #pragma unroll
      for (int g = 0; g < 4; ++g) {
        acc[mi][g][0] = 0.f; acc[mi][g][1] = 0.f;
        acc[mi][g][2] = 0.f; acc[mi][g][3] = 0.f;
      }
  };

  // full 128x2048x512 slice GEMM from agent-coherent h buffer
  auto gemm_full = [&](const bf16* h_in) {
    unsigned long long tmp[64];
    #pragma unroll
    for (int q = 0; q < 64; ++q) {
      int u8 = q * 256 + tid;
      int ch = u8 >> 13, rr = (u8 >> 6) & 127, u = u8 & 63;
      tmp[q] = aload64(h_in + (size_t)rr * 512 + ch * 256 + u * 4);
    }
    #pragma unroll
    for (int ch = 0; ch < 2; ++ch) {
      #pragma unroll
      for (int q = 0; q < 32; ++q) {
        int qq = ch * 32 + q;
        int u8 = qq * 256 + tid;
        int rr = (u8 >> 6) & 127, u = u8 & 63;
        int gs = (u >> 1) ^ (rr & 7);
        *(unsigned long long*)(As + (size_t)rr * 256 + gs * 8 + (u & 1) * 4) = tmp[qq];
      }
      __syncthreads();
      #pragma unroll
      for (int kt = 0; kt < 8; ++kt) {
        int cA = (kt * 4 + ku) ^ axor;
        int cB = ((ch * 8 + kt) * 4 + ku) ^ axor;
        bf16x8 af0 = *(const bf16x8*)(As + (size_t)arow0 * 256 + cA * 8);
        bf16x8 af1 = *(const bf16x8*)(As + (size_t)arow1 * 256 + cA * 8);
        #pragma unroll
        for (int g = 0; g < 4; ++g) {
          bf16x8 bv = *(const bf16x8*)(Bs + (size_t)(g * 16 + fr) * 512 + cB * 8);
          acc[0][g] = __builtin_amdgcn_mfma_f32_16x16x32_bf16(af0, bv, acc[0][g], 0, 0, 0);
          acc[1][g] = __builtin_amdgcn_mfma_f32_16x16x32_bf16(af1, bv, acc[1][g], 0, 0, 0);
        }
      }
      __syncthreads();
    }
  };

  float cr[2][4] = {{0.f,0.f,0.f,0.f},{0.f,0.f,0.f,0.f}};
  float c0r[2][4] = {{0.f,0.f,0.f,0.f},{0.f,0.f,0.f,0.f}};
  bf16 hout[2][4];

  auto pointwise = [&](const bf16* preT) {
    #pragma unroll
    for (int mi = 0; mi < 2; ++mi) {
      int rbase = mi ? row1 : row0;
      int hcol = n0 + fr;
      bf16x4 gv[4];
      #pragma unroll
      for (int g = 0; g < 4; ++g)
        gv[g] = *(const bf16x4*)(preT + ((size_t)(g * 512 + hcol)) * 128 + rbase);
      #pragma unroll
      for (int j = 0; j < 4; ++j) {
        float gi = acc[mi][0][j] + (float)gv[0][j];
        float gf = acc[mi][1][j] + (float)gv[1][j];
        float gg = acc[mi][2][j] + (float)gv[2][j];
        float go = acc[mi][3][j] + (float)gv[3][j];
        float cn = sigf(gf) * cr[mi][j] + sigf(gi) * tanhf(gg);
        float hn = sigf(go) * tanhf(cn);
        cr[mi][j] = cn;
        hout[mi][j] = (bf16)hn;
      }
    }
  };

  // LDS-bounce the block's 128x16 h tile, then 8B agent-scope stores
  auto bounce_store = [&](bf16* hdst, bf16* hsdst, int t, int is_enc) {
    #pragma unroll
    for (int mi = 0; mi < 2; ++mi) {
      int rbase = mi ? row1 : row0;
      #pragma unroll
      for (int j = 0; j < 4; ++j)
        As[(size_t)(rbase + j) * 16 + fr] = hout[mi][j];
    }
    __syncthreads();
    unsigned long long v0 = *(unsigned long long*)(As + (size_t)brow * 16 + bhalf * 8);
    unsigned long long v1 = *(unsigned long long*)(As + (size_t)brow * 16 + bhalf * 8 + 4);
    size_t off = (size_t)brow * 512 + n0 + bhalf * 8;
    astore64(hdst + off, v0);
    astore64(hdst + off + 4, v1);
    if (is_enc) {
      unsigned long long m0 = (t < blen) ? v0 : 0ull;
      unsigned long long m1 = (t < blen) ? v1 : 0ull;
      astore64(hsdst + off, m0);
      astore64(hsdst + off + 4, m1);
      if (t == blen - 1) {
        astore64(h0b + off, v0);
        astore64(h0b + off + 4, v1);
      }
    }
  };

  unsigned hatt[4];
  auto load_hatt = [&](const bf16* h_in) {
    #pragma unroll
    for (int e = 0; e < 4; ++e)
      hatt[e] = aload32(h_in + (size_t)batt * 512 + lane * 2 + 128 * e);
  };

  unsigned hsr[8][4];

  auto attention = [&](int tprev) {
    float sc[8];
    #pragma unroll
    for (int l = 0; l < 8; ++l) {
      float p = 0.f;
      #pragma unroll
      for (int e = 0; e < 4; ++e)
        p += bflo(hatt[e]) * bflo(hsr[l][e]) + bfhi(hatt[e]) * bfhi(hsr[l][e]);
      #pragma unroll
      for (int off = 32; off; off >>= 1) p += __shfl_xor(p, off);
      sc[l] = p;
    }
    float m = -1e30f;
    #pragma unroll
    for (int l = 0; l < 8; ++l) m = fmaxf(m, (l < lenb) ? sc[l] : -1e30f);
    float wgt[8]; float den = 0.f;
    #pragma unroll
    for (int l = 0; l < 8; ++l) { wgt[l] = (l < lenb) ? expf(sc[l] - m) : 0.f; den += wgt[l]; }
    float inv = 1.f / den;
    bf16* dst = Hcat + ((size_t)tprev * 128 + batt) * 1024;
    #pragma unroll
    for (int e = 0; e < 4; ++e) {
      float clo = 0.f, chi = 0.f;
      #pragma unroll
      for (int l = 0; l < 8; ++l) {
        clo += wgt[l] * bflo(hsr[l][e]);
        chi += wgt[l] * bfhi(hsr[l][e]);
      }
      *(unsigned*)(dst + 512 + lane * 2 + 128 * e) = packbf(clo * inv, chi * inv);
      *(unsigned*)(dst + lane * 2 + 128 * e) = hatt[e];
    }
  };

  // ---------------- encoder ----------------
  loadB(WhhE);
  __syncthreads();
  for (int t = 0; t < 8; ++t) {
    zacc();
    if (t > 0) {
      waitall(cnt + (t - 1));
      gemm_full(hS + (size_t)(t - 1) * 65536);
    }
    pointwise(preEncT + (size_t)t * 262144);
    #pragma unroll
    for (int mi = 0; mi < 2; ++mi)
      #pragma unroll
      for (int j = 0; j < 4; ++j)
        if (t == lenr[mi][j] - 1) c0r[mi][j] = cr[mi][j];
    bounce_store(hS + (size_t)t * 65536, hsEnc + (size_t)t * 65536, t, 1);
    arrive(cnt + t);
  }

  // ---------------- switch to decoder ----------------
  __syncthreads();
  loadB(WhhD);
  __syncthreads();
  waitall(cnt + 7);
  #pragma unroll
  for (int l = 0; l < 8; ++l)
    #pragma unroll
    for (int e = 0; e < 4; ++e)
      hsr[l][e] = aload32(hsEnc + ((size_t)l * 128 + batt) * 512 + lane * 2 + 128 * e);
  #pragma unroll
  for (int mi = 0; mi < 2; ++mi)
    #pragma unroll
    for (int j = 0; j < 4; ++j) cr[mi][j] = c0r[mi][j];

  // ---------------- decoder ----------------
  for (int t = 0; t < 48; ++t) {
    zacc();
    const bf16* hin;
    if (t == 0) {
      hin = h0b;
    } else {
      waitall(cnt + (8 + t - 1));
      hin = hS + (size_t)(8 + t - 1) * 65536;
    }
    if (t >= 1) load_hatt(hin);
    gemm_full(hin);
    pointwise(preDecT + (size_t)t * 262144);
    bounce_store(hS + (size_t)(8 + t) * 65536, nullptr, t, 0);
    arrive(cnt + 8 + t);
    if (t >= 1) attention(t - 1);
  }
  waitall(cnt + 55);
  load_hatt(hS + (size_t)55 * 65536);
  attention(47);
}

// ---------------------------------------------------------------------------
extern "C" void kernel_launch(void* const* d_in, const int* in_sizes, int n_in,
                              void* d_out, int out_size, void* d_ws, size_t ws_size,
                              hipStream_t stream)
{
  const int* kws  = (const int*)d_in[0];
  const int* poem = (const int*)d_in[1];
  const int* kwl  = (const int*)d_in[2];
  const float* emb  = (const float*)d_in[3];
  const float* eWih = (const float*)d_in[4];
  const float* eWhh = (const float*)d_in[5];
  const float* eb   = (const float*)d_in[6];
  const float* dWih = (const float*)d_in[7];
  const float* dWhh = (const float*)d_in[8];
  const float* db   = (const float*)d_in[9];
  const float* outW = (const float*)d_in[10];
  const float* outb = (const float*)d_in[11];
  float* out = (float*)d_out;

  char* base = (char*)d_ws;
  size_t o = 0;
  auto take = [&](size_t bytes) -> char* {
    char* r = base + o;
    o += (bytes + 255) & ~(size_t)255;
    return r;
  };
  bf16* WihE  = (bf16*)take(2048 * 512 * 2);
  bf16* WhhE  = (bf16*)take(2048 * 512 * 2);
  bf16* WihD  = (bf16*)take(2048 * 512 * 2);
  bf16* WhhD  = (bf16*)take(2048 * 512 * 2);
  bf16* outWb = (bf16*)take((size_t)10112 * 1024 * 2);   // padded to 79*128 rows
  bf16* Xenc  = (bf16*)take(1024 * 512 * 2);
  bf16* Xdec  = (bf16*)take((size_t)6144 * 512 * 2);
  bf16* preEncT = (bf16*)take((size_t)8 * 2048 * 128 * 2);
  bf16* preDecT = (bf16*)take((size_t)48 * 2048 * 128 * 2);
  bf16* Hcat   = (bf16*)take((size_t)6144 * 1024 * 2);
  bf16* hS     = (bf16*)take((size_t)56 * 65536 * 2);
  bf16* hsEnc  = (bf16*)take((size_t)8 * 128 * 512 * 2);
  bf16* h0b    = (bf16*)take(128 * 512 * 2);
  unsigned* cnt = (unsigned*)take(256);

  prep_kernel<<<4096, 256, 0, stream>>>(kws, poem, emb, eWih, eWhh, dWih, dWhh, outW,
                                        WihE, WhhE, WihD, WhhD, outWb, Xenc, Xdec, cnt);

  // pre-gates (bias folded), stored transposed [t][2048][128]
  gemm2_kernel<3><<<128, 256, 0, stream>>>(Xenc, WihE, eb, preEncT, 1024, 2048, 512, 8);
  gemm2_kernel<3><<<768, 256, 0, stream>>>(Xdec, WihD, db, preDecT, 6144, 2048, 512, 48);

  // persistent encoder + decoder + attention
  recurrent_kernel<<<NBLK_REC, 256, 0, stream>>>(preEncT, preDecT, WhhE, WhhD, kwl,
                                                 hS, h0b, hsEnc, Hcat, cnt);

  // final projection: [h|ctx] @ out_W^T + out_b, scattered to [B,T,V]
  gemm2_kernel<2><<<3792, 256, 0, stream>>>(Hcat, outWb, outb, out, 6144, 10000, 1024, 48);
}

// Round 4
// 888.375 us; speedup vs baseline: 1.2752x; 1.0052x over previous
//
#include <hip/hip_runtime.h>
#include <hip/hip_bf16.h>

typedef __bf16 bf16;
typedef __attribute__((ext_vector_type(8))) __bf16 bf16x8;
typedef __attribute__((ext_vector_type(4))) __bf16 bf16x4;
typedef __attribute__((ext_vector_type(4))) float f32x4;

#define B_ 128
#define L_ 8
#define T_ 48
#define V_ 10000
#define NBLK_REC 32

__device__ __forceinline__ float sigf(float x) { return 1.f / (1.f + expf(-x)); }

__device__ __forceinline__ void gl_lds16(const bf16* g, bf16* l) {
  __builtin_amdgcn_global_load_lds(
      (const __attribute__((address_space(1))) unsigned int*)g,
      (__attribute__((address_space(3))) unsigned int*)l, 16, 0, 0);
}

__device__ __forceinline__ unsigned long long aload64(const void* p) {
  return __hip_atomic_load((unsigned long long*)p, __ATOMIC_RELAXED, __HIP_MEMORY_SCOPE_AGENT);
}
__device__ __forceinline__ unsigned aload32(const void* p) {
  return __hip_atomic_load((unsigned*)p, __ATOMIC_RELAXED, __HIP_MEMORY_SCOPE_AGENT);
}
__device__ __forceinline__ void astore64(void* p, unsigned long long v) {
  __hip_atomic_store((unsigned long long*)p, v, __ATOMIC_RELAXED, __HIP_MEMORY_SCOPE_AGENT);
}
__device__ __forceinline__ float bflo(unsigned u) { return __uint_as_float(u << 16); }
__device__ __forceinline__ float bfhi(unsigned u) { return __uint_as_float(u & 0xffff0000u); }
__device__ __forceinline__ unsigned packbf(float lo, float hi) {
  bf16 a = (bf16)lo, b = (bf16)hi;
  unsigned short ua = __builtin_bit_cast(unsigned short, a);
  unsigned short ub = __builtin_bit_cast(unsigned short, b);
  return (unsigned)ua | ((unsigned)ub << 16);
}

// per-block monotonic completion flags, 128B apart (no RMW, no line ping-pong)
__device__ __forceinline__ void signal(unsigned* flg, int blk, unsigned step) {
  asm volatile("s_waitcnt vmcnt(0)" ::: "memory");  // drain this thread's h stores
  __syncthreads();                                  // all threads drained
  if (threadIdx.x == 0)
    __hip_atomic_store(flg + blk * 32, step, __ATOMIC_RELAXED, __HIP_MEMORY_SCOPE_AGENT);
}
__device__ __forceinline__ void waitstep(const unsigned* flg, unsigned step) {
  if (threadIdx.x < 64) {
    int lane = threadIdx.x;
    for (;;) {
      unsigned v = (lane < NBLK_REC) ? aload32(flg + lane * 32) : step;
      if (__all((int)(v >= step))) break;
      __builtin_amdgcn_s_sleep(1);
    }
  }
  __syncthreads();
}

// ---------------------------------------------------------------------------
// Prep: cast weights f32->bf16 (outW padded to 10112 rows), gather embeddings,
// zero completion flags.
// ---------------------------------------------------------------------------
__global__ void prep_kernel(
    const int* __restrict__ kws, const int* __restrict__ poem,
    const float* __restrict__ emb,
    const float* __restrict__ eWih, const float* __restrict__ eWhh,
    const float* __restrict__ dWih, const float* __restrict__ dWhh,
    const float* __restrict__ outW,
    bf16* __restrict__ WihE, bf16* __restrict__ WhhE,
    bf16* __restrict__ WihD, bf16* __restrict__ WhhD,
    bf16* __restrict__ outWb,
    bf16* __restrict__ Xenc, bf16* __restrict__ Xdec,
    unsigned* __restrict__ flg)
{
  if (blockIdx.x == 0)
    for (int i = threadIdx.x; i < 1024; i += blockDim.x) flg[i] = 0u;
  const long SW = 1048576;       // 2048*512
  const long SOWP = 10354688;    // 10112*1024 (padded)
  const long SXE = 524288;       // 1024*512
  const long SXD = 3145728;      // 6144*512
  const long total = 4 * SW + SOWP + SXE + SXD;
  for (long i = blockIdx.x * (long)blockDim.x + threadIdx.x; i < total;
       i += (long)gridDim.x * blockDim.x) {
    long j = i;
    if (j < SW) { WihE[j] = (bf16)eWih[j]; continue; } j -= SW;
    if (j < SW) { WhhE[j] = (bf16)eWhh[j]; continue; } j -= SW;
    if (j < SW) { WihD[j] = (bf16)dWih[j]; continue; } j -= SW;
    if (j < SW) { WhhD[j] = (bf16)dWhh[j]; continue; } j -= SW;
    if (j < SOWP) {
      long r = j >> 10;
      outWb[j] = (r < 10000) ? (bf16)outW[j] : (bf16)0.f;
      continue;
    } j -= SOWP;
    if (j < SXE) {
      int e = (int)(j & 511); int b = (int)((j >> 9) & 127); int l = (int)(j >> 16);
      int tok = kws[b * L_ + l];
      Xenc[j] = (bf16)emb[(long)tok * 512 + e];
      continue;
    } j -= SXE;
    {
      int e = (int)(j & 511); int b = (int)((j >> 9) & 127); int t = (int)(j >> 16);
      int tok = poem[b * T_ + t];
      Xdec[j] = (bf16)emb[(long)tok * 512 + e];
    }
  }
}

// ---------------------------------------------------------------------------
// m97-structure NT GEMM: C[M,N] = A[M,K]*B[N,K]^T + bias.
// MODE 2: scatter f32 to out[b][t][V] (row = t*128+b).
// MODE 3: bf16 transposed pre-gate store [t][2048][128].
// ---------------------------------------------------------------------------
template<int MODE>
__global__ __launch_bounds__(256) void gemm2_kernel(
    const bf16* __restrict__ A, const bf16* __restrict__ Bm,
    const float* __restrict__ bias, void* __restrict__ outp,
    int M, int N, int K, int MT)
{
  __shared__ bf16 As[128 * 32];
  __shared__ bf16 Bs[128 * 32];
  const int tid = threadIdx.x, lane = tid & 63, wid = tid >> 6;
  const int nwg = gridDim.x;
  int bid = blockIdx.x;
  int swz = ((nwg & 7) == 0) ? ((bid & 7) * (nwg >> 3) + (bid >> 3)) : bid;
  const int tm = swz % MT, tn = swz / MT;
  const int m0 = tm * 128, n0 = tn * 128;
  const int wm = (wid >> 1) * 64, wn = (wid & 1) * 64;
  const int fr = lane & 15, ku = lane >> 4;

  f32x4 acc[4][4];
  #pragma unroll
  for (int mi = 0; mi < 4; ++mi)
    #pragma unroll
    for (int ni = 0; ni < 4; ++ni) {
      acc[mi][ni][0] = 0.f; acc[mi][ni][1] = 0.f;
      acc[mi][ni][2] = 0.f; acc[mi][ni][3] = 0.f;
    }

  for (int kt = 0; kt < K; kt += 32) {
    #pragma unroll
    for (int j = 0; j < 2; ++j) {
      int i0 = j * 256 + wid * 64;
      int i = i0 + lane;
      int r = i >> 2, ub = i & 3;
      gl_lds16(A + (size_t)(m0 + r) * K + kt + ub * 8, As + (size_t)i0 * 8);
      gl_lds16(Bm + (size_t)(n0 + r) * K + kt + ub * 8, Bs + (size_t)i0 * 8);
    }
    __syncthreads();
    bf16x8 af[4], bfr[4];
    #pragma unroll
    for (int mi = 0; mi < 4; ++mi)
      af[mi] = *(const bf16x8*)(As + (size_t)(wm + mi * 16 + fr) * 32 + ku * 8);
    #pragma unroll
    for (int ni = 0; ni < 4; ++ni)
      bfr[ni] = *(const bf16x8*)(Bs + (size_t)(wn + ni * 16 + fr) * 32 + ku * 8);
    #pragma unroll
    for (int mi = 0; mi < 4; ++mi)
      #pragma unroll
      for (int ni = 0; ni < 4; ++ni)
        acc[mi][ni] = __builtin_amdgcn_mfma_f32_16x16x32_bf16(af[mi], bfr[ni], acc[mi][ni], 0, 0, 0);
    __syncthreads();
  }

  const int fq = (lane >> 4) * 4;
  #pragma unroll
  for (int mi = 0; mi < 4; ++mi) {
    #pragma unroll
    for (int ni = 0; ni < 4; ++ni) {
      #pragma unroll
      for (int j = 0; j < 4; ++j) {
        int r = m0 + wm + mi * 16 + fq + j;
        int cix = n0 + wn + ni * 16 + fr;
        if (cix < N) {
          float v = acc[mi][ni][j] + bias[cix];
          if (MODE == 2) {
            int b = r & 127, t = r >> 7;
            ((float*)outp)[(size_t)b * (T_ * V_) + (size_t)t * V_ + cix] = v;
          } else {
            ((bf16*)outp)[((size_t)(r >> 7) * 2048 + cix) * 128 + (r & 127)] = (bf16)v;
          }
        }
      }
    }
  }
}

// ---------------------------------------------------------------------------
// Persistent recurrent kernel. Cross-block h via relaxed agent-scope atomics;
// per-block monotonic flag barrier; c-state in registers.
// ---------------------------------------------------------------------------
__global__ __launch_bounds__(256, 1) void recurrent_kernel(
    const bf16* __restrict__ preEncT, const bf16* __restrict__ preDecT,
    const bf16* __restrict__ WhhE, const bf16* __restrict__ WhhD,
    const int* __restrict__ kwl,
    bf16* __restrict__ hS,      // 56 slots of 128*512 (enc t -> t, dec t -> 8+t)
    bf16* __restrict__ h0b,
    bf16* __restrict__ hsEnc,   // [8][128][512]
    bf16* __restrict__ Hcat,    // [48][128][1024]
    unsigned* __restrict__ flg)
{
  __shared__ bf16 Bs[64 * 512];    // persistent Whh slice, XOR-swizzled
  __shared__ bf16 As[128 * 256];   // h half (256 K-cols), XOR-swizzled; also bounce buf
  const int tid = threadIdx.x, lane = tid & 63, wid = tid >> 6;
  const int blk = blockIdx.x, n0 = blk * 16;
  const int fr = lane & 15, fq = (lane >> 4) * 4, ku = lane >> 4;
  const int axor = fr & 7;
  const int arow0 = wid * 32 + fr, arow1 = wid * 32 + 16 + fr;
  const int row0 = wid * 32 + fq, row1 = wid * 32 + 16 + fq;
  const int brow = tid >> 1, bhalf = tid & 1;
  const int blen = kwl[brow];
  const int batt = blk * 4 + wid;
  const int lenb = kwl[batt];
  int lenr[2][4];
  #pragma unroll
  for (int j = 0; j < 4; ++j) { lenr[0][j] = kwl[row0 + j]; lenr[1][j] = kwl[row1 + j]; }

  auto loadB = [&](const bf16* W) {
    #pragma unroll
    for (int j = 0; j < 16; ++j) {
      int i = j * 256 + tid;
      int r = i >> 6, u = i & 63;
      int p = u ^ (r & 7);
      bf16x8 v = *(const bf16x8*)(W + (size_t)((r >> 4) * 512 + n0 + (r & 15)) * 512 + u * 8);
      *(bf16x8*)(Bs + (size_t)r * 512 + p * 8) = v;
    }
  };

  f32x4 acc[2][4];
  auto zacc = [&]() {
    #pragma unroll
    for (int mi = 0; mi < 2; ++mi)
      #pragma unroll
      for (int g = 0; g < 4; ++g) {
        acc[mi][g][0] = 0.f; acc[mi][g][1] = 0.f;
        acc[mi][g][2] = 0.f; acc[mi][g][3] = 0.f;
      }
  };

  // full 128x(4x16)x512 slice GEMM from agent-coherent h buffer
  auto gemm_full = [&](const bf16* h_in) {
    unsigned long long tmp[64];
    #pragma unroll
    for (int q = 0; q < 64; ++q) {
      int u8 = q * 256 + tid;
      int ch = u8 >> 13, rr = (u8 >> 6) & 127, u = u8 & 63;
      tmp[q] = aload64(h_in + (size_t)rr * 512 + ch * 256 + u * 4);
    }
    #pragma unroll
    for (int ch = 0; ch < 2; ++ch) {
      #pragma unroll
      for (int q = 0; q < 32; ++q) {
        int qq = ch * 32 + q;
        int u8 = qq * 256 + tid;
        int rr = (u8 >> 6) & 127, u = u8 & 63;
        int gs = (u >> 1) ^ (rr & 7);
        *(unsigned long long*)(As + (size_t)rr * 256 + gs * 8 + (u & 1) * 4) = tmp[qq];
      }
      __syncthreads();
      #pragma unroll
      for (int kt = 0; kt < 8; ++kt) {
        int cA = (kt * 4 + ku) ^ axor;
        int cB = ((ch * 8 + kt) * 4 + ku) ^ axor;
        bf16x8 af0 = *(const bf16x8*)(As + (size_t)arow0 * 256 + cA * 8);
        bf16x8 af1 = *(const bf16x8*)(As + (size_t)arow1 * 256 + cA * 8);
        #pragma unroll
        for (int g = 0; g < 4; ++g) {
          bf16x8 bv = *(const bf16x8*)(Bs + (size_t)(g * 16 + fr) * 512 + cB * 8);
          acc[0][g] = __builtin_amdgcn_mfma_f32_16x16x32_bf16(af0, bv, acc[0][g], 0, 0, 0);
          acc[1][g] = __builtin_amdgcn_mfma_f32_16x16x32_bf16(af1, bv, acc[1][g], 0, 0, 0);
        }
      }
      __syncthreads();
    }
  };

  float cr[2][4] = {{0.f,0.f,0.f,0.f},{0.f,0.f,0.f,0.f}};
  float c0r[2][4] = {{0.f,0.f,0.f,0.f},{0.f,0.f,0.f,0.f}};
  bf16 hout[2][4];

  bf16x4 gv[2][4];
  auto prefg = [&](const bf16* preT) {
    #pragma unroll
    for (int mi = 0; mi < 2; ++mi) {
      int rbase = mi ? row1 : row0;
      int hcol = n0 + fr;
      #pragma unroll
      for (int g = 0; g < 4; ++g)
        gv[mi][g] = *(const bf16x4*)(preT + ((size_t)(g * 512 + hcol)) * 128 + rbase);
    }
  };

  auto pointwise = [&]() {
    #pragma unroll
    for (int mi = 0; mi < 2; ++mi) {
      #pragma unroll
      for (int j = 0; j < 4; ++j) {
        float gi = acc[mi][0][j] + (float)gv[mi][0][j];
        float gf = acc[mi][1][j] + (float)gv[mi][1][j];
        float gg = acc[mi][2][j] + (float)gv[mi][2][j];
        float go = acc[mi][3][j] + (float)gv[mi][3][j];
        float cn = sigf(gf) * cr[mi][j] + sigf(gi) * tanhf(gg);
        float hn = sigf(go) * tanhf(cn);
        cr[mi][j] = cn;
        hout[mi][j] = (bf16)hn;
      }
    }
  };

  // LDS-bounce the block's 128x16 h tile, then 8B agent-scope stores
  auto bounce_store = [&](bf16* hdst, bf16* hsdst, int t, int is_enc) {
    #pragma unroll
    for (int mi = 0; mi < 2; ++mi) {
      int rbase = mi ? row1 : row0;
      #pragma unroll
      for (int j = 0; j < 4; ++j)
        As[(size_t)(rbase + j) * 16 + fr] = hout[mi][j];
    }
    __syncthreads();
    unsigned long long v0 = *(unsigned long long*)(As + (size_t)brow * 16 + bhalf * 8);
    unsigned long long v1 = *(unsigned long long*)(As + (size_t)brow * 16 + bhalf * 8 + 4);
    size_t off = (size_t)brow * 512 + n0 + bhalf * 8;
    astore64(hdst + off, v0);
    astore64(hdst + off + 4, v1);
    if (is_enc) {
      unsigned long long m0 = (t < blen) ? v0 : 0ull;
      unsigned long long m1 = (t < blen) ? v1 : 0ull;
      astore64(hsdst + off, m0);
      astore64(hsdst + off + 4, m1);
      if (t == blen - 1) {
        astore64(h0b + off, v0);
        astore64(h0b + off + 4, v1);
      }
    }
  };

  unsigned hatt[4];
  auto load_hatt = [&](const bf16* h_in) {
    #pragma unroll
    for (int e = 0; e < 4; ++e)
      hatt[e] = aload32(h_in + (size_t)batt * 512 + lane * 2 + 128 * e);
  };

  unsigned hsr[8][4];

  auto attention = [&](int tprev) {
    float sc[8];
    #pragma unroll
    for (int l = 0; l < 8; ++l) {
      float p = 0.f;
      #pragma unroll
      for (int e = 0; e < 4; ++e)
        p += bflo(hatt[e]) * bflo(hsr[l][e]) + bfhi(hatt[e]) * bfhi(hsr[l][e]);
      #pragma unroll
      for (int off = 32; off; off >>= 1) p += __shfl_xor(p, off);
      sc[l] = p;
    }
    float m = -1e30f;
    #pragma unroll
    for (int l = 0; l < 8; ++l) m = fmaxf(m, (l < lenb) ? sc[l] : -1e30f);
    float wgt[8]; float den = 0.f;
    #pragma unroll
    for (int l = 0; l < 8; ++l) { wgt[l] = (l < lenb) ? expf(sc[l] - m) : 0.f; den += wgt[l]; }
    float inv = 1.f / den;
    bf16* dst = Hcat + ((size_t)tprev * 128 + batt) * 1024;
    #pragma unroll
    for (int e = 0; e < 4; ++e) {
      float clo = 0.f, chi = 0.f;
      #pragma unroll
      for (int l = 0; l < 8; ++l) {
        clo += wgt[l] * bflo(hsr[l][e]);
        chi += wgt[l] * bfhi(hsr[l][e]);
      }
      *(unsigned*)(dst + 512 + lane * 2 + 128 * e) = packbf(clo * inv, chi * inv);
      *(unsigned*)(dst + lane * 2 + 128 * e) = hatt[e];
    }
  };

  // ---------------- encoder ----------------
  loadB(WhhE);
  __syncthreads();
  for (int t = 0; t < 8; ++t) {
    prefg(preEncT + (size_t)t * 262144);   // independent of other blocks: issue early
    zacc();
    if (t > 0) {
      waitstep(flg, (unsigned)t);
      gemm_full(hS + (size_t)(t - 1) * 65536);
    }
    pointwise();
    #pragma unroll
    for (int mi = 0; mi < 2; ++mi)
      #pragma unroll
      for (int j = 0; j < 4; ++j)
        if (t == lenr[mi][j] - 1) c0r[mi][j] = cr[mi][j];
    bounce_store(hS + (size_t)t * 65536, hsEnc + (size_t)t * 65536, t, 1);
    signal(flg, blk, (unsigned)(t + 1));
  }

  // ---------------- switch to decoder ----------------
  __syncthreads();
  loadB(WhhD);
  __syncthreads();
  waitstep(flg, 8u);
  #pragma unroll
  for (int l = 0; l < 8; ++l)
    #pragma unroll
    for (int e = 0; e < 4; ++e)
      hsr[l][e] = aload32(hsEnc + ((size_t)l * 128 + batt) * 512 + lane * 2 + 128 * e);
  #pragma unroll
  for (int mi = 0; mi < 2; ++mi)
    #pragma unroll
    for (int j = 0; j < 4; ++j) cr[mi][j] = c0r[mi][j];

  // ---------------- decoder ----------------
  for (int t = 0; t < 48; ++t) {
    prefg(preDecT + (size_t)t * 262144);
    zacc();
    const bf16* hin = (t == 0) ? (const bf16*)h0b : (const bf16*)(hS + (size_t)(8 + t - 1) * 65536);
    waitstep(flg, (unsigned)(8 + t));
    if (t >= 1) load_hatt(hin);
    gemm_full(hin);
    pointwise();
    bounce_store(hS + (size_t)(8 + t) * 65536, nullptr, t, 0);
    signal(flg, blk, (unsigned)(9 + t));
    if (t >= 1) attention(t - 1);
  }
  waitstep(flg, 56u);
  load_hatt(hS + (size_t)55 * 65536);
  attention(47);
}

// ---------------------------------------------------------------------------
extern "C" void kernel_launch(void* const* d_in, const int* in_sizes, int n_in,
                              void* d_out, int out_size, void* d_ws, size_t ws_size,
                              hipStream_t stream)
{
  const int* kws  = (const int*)d_in[0];
  const int* poem = (const int*)d_in[1];
  const int* kwl  = (const int*)d_in[2];
  const float* emb  = (const float*)d_in[3];
  const float* eWih = (const float*)d_in[4];
  const float* eWhh = (const float*)d_in[5];
  const float* eb   = (const float*)d_in[6];
  const float* dWih = (const float*)d_in[7];
  const float* dWhh = (const float*)d_in[8];
  const float* db   = (const float*)d_in[9];
  const float* outW = (const float*)d_in[10];
  const float* outb = (const float*)d_in[11];
  float* out = (float*)d_out;

  char* base = (char*)d_ws;
  size_t o = 0;
  auto take = [&](size_t bytes) -> char* {
    char* r = base + o;
    o += (bytes + 255) & ~(size_t)255;
    return r;
  };
  bf16* WihE  = (bf16*)take(2048 * 512 * 2);
  bf16* WhhE  = (bf16*)take(2048 * 512 * 2);
  bf16* WihD  = (bf16*)take(2048 * 512 * 2);
  bf16* WhhD  = (bf16*)take(2048 * 512 * 2);
  bf16* outWb = (bf16*)take((size_t)10112 * 1024 * 2);   // padded to 79*128 rows
  bf16* Xenc  = (bf16*)take(1024 * 512 * 2);
  bf16* Xdec  = (bf16*)take((size_t)6144 * 512 * 2);
  bf16* preEncT = (bf16*)take((size_t)8 * 2048 * 128 * 2);
  bf16* preDecT = (bf16*)take((size_t)48 * 2048 * 128 * 2);
  bf16* Hcat   = (bf16*)take((size_t)6144 * 1024 * 2);
  bf16* hS     = (bf16*)take((size_t)56 * 65536 * 2);
  bf16* hsEnc  = (bf16*)take((size_t)8 * 128 * 512 * 2);
  bf16* h0b    = (bf16*)take(128 * 512 * 2);
  unsigned* flg = (unsigned*)take(4096);

  prep_kernel<<<4096, 256, 0, stream>>>(kws, poem, emb, eWih, eWhh, dWih, dWhh, outW,
                                        WihE, WhhE, WihD, WhhD, outWb, Xenc, Xdec, flg);

  // pre-gates (bias folded), stored transposed [t][2048][128]
  gemm2_kernel<3><<<128, 256, 0, stream>>>(Xenc, WihE, eb, preEncT, 1024, 2048, 512, 8);
  gemm2_kernel<3><<<768, 256, 0, stream>>>(Xdec, WihD, db, preDecT, 6144, 2048, 512, 48);

  // persistent encoder + decoder + attention
  recurrent_kernel<<<NBLK_REC, 256, 0, stream>>>(preEncT, preDecT, WhhE, WhhD, kwl,
                                                 hS, h0b, hsEnc, Hcat, flg);

  // final projection: [h|ctx] @ out_W^T + out_b, scattered to [B,T,V]
  gemm2_kernel<2><<<3792, 256, 0, stream>>>(Hcat, outWb, outb, out, 6144, 10000, 1024, 48);
}

// Round 5
// 788.064 us; speedup vs baseline: 1.4376x; 1.1273x over previous
//
#include <hip/hip_runtime.h>
#include <hip/hip_bf16.h>

typedef __bf16 bf16;
typedef __attribute__((ext_vector_type(8))) __bf16 bf16x8;
typedef __attribute__((ext_vector_type(4))) __bf16 bf16x4;
typedef __attribute__((ext_vector_type(4))) float f32x4;

#define B_ 128
#define L_ 8
#define T_ 48
#define V_ 10000
#define NBLK_REC 32

__device__ __forceinline__ float sigf(float x) { return 1.f / (1.f + expf(-x)); }

__device__ __forceinline__ void gl_lds16(const bf16* g, bf16* l) {
  __builtin_amdgcn_global_load_lds(
      (const __attribute__((address_space(1))) unsigned int*)g,
      (__attribute__((address_space(3))) unsigned int*)l, 16, 0, 0);
}

__device__ __forceinline__ unsigned aload32(const void* p) {
  return __hip_atomic_load((unsigned*)p, __ATOMIC_RELAXED, __HIP_MEMORY_SCOPE_AGENT);
}
__device__ __forceinline__ void astore64(void* p, unsigned long long v) {
  __hip_atomic_store((unsigned long long*)p, v, __ATOMIC_RELAXED, __HIP_MEMORY_SCOPE_AGENT);
}
__device__ __forceinline__ float bflo(unsigned u) { return __uint_as_float(u << 16); }
__device__ __forceinline__ float bfhi(unsigned u) { return __uint_as_float(u & 0xffff0000u); }
__device__ __forceinline__ unsigned packbf(float lo, float hi) {
  bf16 a = (bf16)lo, b = (bf16)hi;
  unsigned short ua = __builtin_bit_cast(unsigned short, a);
  unsigned short ub = __builtin_bit_cast(unsigned short, b);
  return (unsigned)ua | ((unsigned)ub << 16);
}

// per-block monotonic completion flags, 128B apart
__device__ __forceinline__ void signal(unsigned* flg, int blk, unsigned step) {
  asm volatile("s_waitcnt vmcnt(0)" ::: "memory");  // drain this thread's h stores
  __syncthreads();                                  // all threads drained
  if (threadIdx.x == 0)
    __hip_atomic_store(flg + blk * 32, step, __ATOMIC_RELAXED, __HIP_MEMORY_SCOPE_AGENT);
}
__device__ __forceinline__ void waitstep(const unsigned* flg, unsigned step) {
  if (threadIdx.x < 64) {
    int lane = threadIdx.x;
    for (;;) {
      unsigned v = (lane < NBLK_REC) ? aload32(flg + lane * 32) : step;
      if (__all((int)(v >= step))) break;
      __builtin_amdgcn_s_sleep(1);
    }
  }
  __syncthreads();
}

// ---------------------------------------------------------------------------
// Prep: cast weights f32->bf16 (outW padded to 10112 rows), gather embeddings,
// zero completion flags.
// ---------------------------------------------------------------------------
__global__ void prep_kernel(
    const int* __restrict__ kws, const int* __restrict__ poem,
    const float* __restrict__ emb,
    const float* __restrict__ eWih, const float* __restrict__ eWhh,
    const float* __restrict__ dWih, const float* __restrict__ dWhh,
    const float* __restrict__ outW,
    bf16* __restrict__ WihE, bf16* __restrict__ WhhE,
    bf16* __restrict__ WihD, bf16* __restrict__ WhhD,
    bf16* __restrict__ outWb,
    bf16* __restrict__ Xenc, bf16* __restrict__ Xdec,
    unsigned* __restrict__ flg)
{
  if (blockIdx.x == 0)
    for (int i = threadIdx.x; i < 1024; i += blockDim.x) flg[i] = 0u;
  const long SW = 1048576;       // 2048*512
  const long SOWP = 10354688;    // 10112*1024 (padded)
  const long SXE = 524288;       // 1024*512
  const long SXD = 3145728;      // 6144*512
  const long total = 4 * SW + SOWP + SXE + SXD;
  for (long i = blockIdx.x * (long)blockDim.x + threadIdx.x; i < total;
       i += (long)gridDim.x * blockDim.x) {
    long j = i;
    if (j < SW) { WihE[j] = (bf16)eWih[j]; continue; } j -= SW;
    if (j < SW) { WhhE[j] = (bf16)eWhh[j]; continue; } j -= SW;
    if (j < SW) { WihD[j] = (bf16)dWih[j]; continue; } j -= SW;
    if (j < SW) { WhhD[j] = (bf16)dWhh[j]; continue; } j -= SW;
    if (j < SOWP) {
      long r = j >> 10;
      outWb[j] = (r < 10000) ? (bf16)outW[j] : (bf16)0.f;
      continue;
    } j -= SOWP;
    if (j < SXE) {
      int e = (int)(j & 511); int b = (int)((j >> 9) & 127); int l = (int)(j >> 16);
      int tok = kws[b * L_ + l];
      Xenc[j] = (bf16)emb[(long)tok * 512 + e];
      continue;
    } j -= SXE;
    {
      int e = (int)(j & 511); int b = (int)((j >> 9) & 127); int t = (int)(j >> 16);
      int tok = poem[b * T_ + t];
      Xdec[j] = (bf16)emb[(long)tok * 512 + e];
    }
  }
}

// ---------------------------------------------------------------------------
// m97-structure NT GEMM: C[M,N] = A[M,K]*B[N,K]^T + bias.
// MODE 2: scatter f32 to out[b][t][V] (row = t*128+b); XCD-banded tile order
//         (A band L2-resident per XCD, B swept in sync through MALL).
// MODE 3: bf16 transposed pre-gate store [t][2048][128].
// ---------------------------------------------------------------------------
template<int MODE>
__global__ __launch_bounds__(256) void gemm2_kernel(
    const bf16* __restrict__ A, const bf16* __restrict__ Bm,
    const float* __restrict__ bias, void* __restrict__ outp,
    int M, int N, int K, int MT)
{
  __shared__ bf16 As[128 * 32];
  __shared__ bf16 Bs[128 * 32];
  const int tid = threadIdx.x, lane = tid & 63, wid = tid >> 6;
  const int nwg = gridDim.x;
  int bid = blockIdx.x;
  int tm, tn;
  if (MODE == 2) {
    // nwg = 3792 = 8 xcd * 474; per XCD: 6 tm rows (A band 1.5MB), tn sweep
    int xcd = bid & 7, idx = bid >> 3;
    tm = xcd * 6 + idx % 6;
    tn = idx / 6;
  } else {
    int swz = ((nwg & 7) == 0) ? ((bid & 7) * (nwg >> 3) + (bid >> 3)) : bid;
    tm = swz % MT; tn = swz / MT;
  }
  const int m0 = tm * 128, n0 = tn * 128;
  const int wm = (wid >> 1) * 64, wn = (wid & 1) * 64;
  const int fr = lane & 15, ku = lane >> 4;

  f32x4 acc[4][4];
  #pragma unroll
  for (int mi = 0; mi < 4; ++mi)
    #pragma unroll
    for (int ni = 0; ni < 4; ++ni) {
      acc[mi][ni][0] = 0.f; acc[mi][ni][1] = 0.f;
      acc[mi][ni][2] = 0.f; acc[mi][ni][3] = 0.f;
    }

  for (int kt = 0; kt < K; kt += 32) {
    #pragma unroll
    for (int j = 0; j < 2; ++j) {
      int i0 = j * 256 + wid * 64;
      int i = i0 + lane;
      int r = i >> 2, ub = i & 3;
      gl_lds16(A + (size_t)(m0 + r) * K + kt + ub * 8, As + (size_t)i0 * 8);
      gl_lds16(Bm + (size_t)(n0 + r) * K + kt + ub * 8, Bs + (size_t)i0 * 8);
    }
    __syncthreads();
    bf16x8 af[4], bfr[4];
    #pragma unroll
    for (int mi = 0; mi < 4; ++mi)
      af[mi] = *(const bf16x8*)(As + (size_t)(wm + mi * 16 + fr) * 32 + ku * 8);
    #pragma unroll
    for (int ni = 0; ni < 4; ++ni)
      bfr[ni] = *(const bf16x8*)(Bs + (size_t)(wn + ni * 16 + fr) * 32 + ku * 8);
    #pragma unroll
    for (int mi = 0; mi < 4; ++mi)
      #pragma unroll
      for (int ni = 0; ni < 4; ++ni)
        acc[mi][ni] = __builtin_amdgcn_mfma_f32_16x16x32_bf16(af[mi], bfr[ni], acc[mi][ni], 0, 0, 0);
    __syncthreads();
  }

  const int fq = (lane >> 4) * 4;
  #pragma unroll
  for (int mi = 0; mi < 4; ++mi) {
    #pragma unroll
    for (int ni = 0; ni < 4; ++ni) {
      #pragma unroll
      for (int j = 0; j < 4; ++j) {
        int r = m0 + wm + mi * 16 + fq + j;
        int cix = n0 + wn + ni * 16 + fr;
        if (cix < N) {
          float v = acc[mi][ni][j] + bias[cix];
          if (MODE == 2) {
            int b = r & 127, t = r >> 7;
            ((float*)outp)[(size_t)b * (T_ * V_) + (size_t)t * V_ + cix] = v;
          } else {
            ((bf16*)outp)[((size_t)(r >> 7) * 2048 + cix) * 128 + (r & 127)] = (bf16)v;
          }
        }
      }
    }
  }
}

// ---------------------------------------------------------------------------
// Persistent recurrent kernel. Cross-block h: coherent asm loads (sc0 sc1) +
// agent-scope stores; per-block monotonic flag barrier; c-state in registers.
// ---------------------------------------------------------------------------
__global__ __launch_bounds__(256, 1) void recurrent_kernel(
    const bf16* __restrict__ preEncT, const bf16* __restrict__ preDecT,
    const bf16* __restrict__ WhhE, const bf16* __restrict__ WhhD,
    const int* __restrict__ kwl,
    bf16* __restrict__ hS,      // 56 slots of 128*512 (enc t -> t, dec t -> 8+t)
    bf16* __restrict__ h0b,
    bf16* __restrict__ hsEnc,   // [8][128][512]
    bf16* __restrict__ Hcat,    // [48][128][1024]
    unsigned* __restrict__ flg)
{
  __shared__ bf16 Bs[64 * 512];    // persistent Whh slice, XOR-swizzled
  __shared__ bf16 As[128 * 256];   // h half (256 K-cols), XOR-swizzled; also bounce buf
  const int tid = threadIdx.x, lane = tid & 63, wid = tid >> 6;
  const int blk = blockIdx.x, n0 = blk * 16;
  const int fr = lane & 15, fq = (lane >> 4) * 4, ku = lane >> 4;
  const int axor = fr & 7;
  const int arow0 = wid * 32 + fr, arow1 = wid * 32 + 16 + fr;
  const int row0 = wid * 32 + fq, row1 = wid * 32 + 16 + fq;
  const int brow = tid >> 1, bhalf = tid & 1;
  const int blen = kwl[brow];
  const int batt = blk * 4 + wid;
  const int lenb = kwl[batt];
  int lenr[2][4];
  #pragma unroll
  for (int j = 0; j < 4; ++j) { lenr[0][j] = kwl[row0 + j]; lenr[1][j] = kwl[row1 + j]; }

  auto loadB = [&](const bf16* W) {
    #pragma unroll
    for (int j = 0; j < 16; ++j) {
      int i = j * 256 + tid;
      int r = i >> 6, u = i & 63;
      int p = u ^ (r & 7);
      bf16x8 v = *(const bf16x8*)(W + (size_t)((r >> 4) * 512 + n0 + (r & 15)) * 512 + u * 8);
      *(bf16x8*)(Bs + (size_t)r * 512 + p * 8) = v;
    }
  };

  f32x4 acc[2][4];
  auto zacc = [&]() {
    #pragma unroll
    for (int mi = 0; mi < 2; ++mi)
      #pragma unroll
      for (int g = 0; g < 4; ++g) {
        acc[mi][g][0] = 0.f; acc[mi][g][1] = 0.f;
        acc[mi][g][2] = 0.f; acc[mi][g][3] = 0.f;
      }
  };

  // full 128x(4x16)x512 slice GEMM; h read via coherent vector loads
  auto gemm_full = [&](const bf16* h_in) {
    #pragma unroll
    for (int ch = 0; ch < 2; ++ch) {
      f32x4 tv[16];
      #pragma unroll
      for (int j = 0; j < 16; ++j) {
        int i = j * 256 + tid;
        int r = i >> 5, up = i & 31;
        const bf16* ga = h_in + (size_t)r * 512 + ch * 256 + up * 8;
        asm volatile("global_load_dwordx4 %0, %1, off sc0 sc1"
                     : "=v"(tv[j]) : "v"(ga) : "memory");
      }
      asm volatile("s_waitcnt vmcnt(0)" ::: "memory");
      __builtin_amdgcn_sched_barrier(0);
      #pragma unroll
      for (int j = 0; j < 16; ++j) {
        int i = j * 256 + tid;
        int r = i >> 5, up = i & 31;
        int s = up ^ (r & 7);
        *(f32x4*)(As + ((size_t)r * 32 + s) * 8) = tv[j];
      }
      __syncthreads();
      #pragma unroll
      for (int kt = 0; kt < 8; ++kt) {
        int cA = (kt * 4 + ku) ^ axor;
        int cB = ((ch * 8 + kt) * 4 + ku) ^ axor;
        bf16x8 af0 = *(const bf16x8*)(As + (size_t)arow0 * 256 + cA * 8);
        bf16x8 af1 = *(const bf16x8*)(As + (size_t)arow1 * 256 + cA * 8);
        #pragma unroll
        for (int g = 0; g < 4; ++g) {
          bf16x8 bv = *(const bf16x8*)(Bs + (size_t)(g * 16 + fr) * 512 + cB * 8);
          acc[0][g] = __builtin_amdgcn_mfma_f32_16x16x32_bf16(af0, bv, acc[0][g], 0, 0, 0);
          acc[1][g] = __builtin_amdgcn_mfma_f32_16x16x32_bf16(af1, bv, acc[1][g], 0, 0, 0);
        }
      }
      __syncthreads();
    }
  };

  float cr[2][4] = {{0.f,0.f,0.f,0.f},{0.f,0.f,0.f,0.f}};
  float c0r[2][4] = {{0.f,0.f,0.f,0.f},{0.f,0.f,0.f,0.f}};
  bf16 hout[2][4];

  bf16x4 gv[2][4];
  auto prefg = [&](const bf16* preT) {
    #pragma unroll
    for (int mi = 0; mi < 2; ++mi) {
      int rbase = mi ? row1 : row0;
      int hcol = n0 + fr;
      #pragma unroll
      for (int g = 0; g < 4; ++g)
        gv[mi][g] = *(const bf16x4*)(preT + ((size_t)(g * 512 + hcol)) * 128 + rbase);
    }
  };

  auto pointwise = [&]() {
    #pragma unroll
    for (int mi = 0; mi < 2; ++mi) {
      #pragma unroll
      for (int j = 0; j < 4; ++j) {
        float gi = acc[mi][0][j] + (float)gv[mi][0][j];
        float gf = acc[mi][1][j] + (float)gv[mi][1][j];
        float gg = acc[mi][2][j] + (float)gv[mi][2][j];
        float go = acc[mi][3][j] + (float)gv[mi][3][j];
        float cn = sigf(gf) * cr[mi][j] + sigf(gi) * tanhf(gg);
        float hn = sigf(go) * tanhf(cn);
        cr[mi][j] = cn;
        hout[mi][j] = (bf16)hn;
      }
    }
  };

  // LDS-bounce the block's 128x16 h tile, then 8B agent-scope stores
  auto bounce_store = [&](bf16* hdst, bf16* hsdst, int t, int is_enc) {
    #pragma unroll
    for (int mi = 0; mi < 2; ++mi) {
      int rbase = mi ? row1 : row0;
      #pragma unroll
      for (int j = 0; j < 4; ++j)
        As[(size_t)(rbase + j) * 16 + fr] = hout[mi][j];
    }
    __syncthreads();
    unsigned long long v0 = *(unsigned long long*)(As + (size_t)brow * 16 + bhalf * 8);
    unsigned long long v1 = *(unsigned long long*)(As + (size_t)brow * 16 + bhalf * 8 + 4);
    size_t off = (size_t)brow * 512 + n0 + bhalf * 8;
    astore64(hdst + off, v0);
    astore64(hdst + off + 4, v1);
    if (is_enc) {
      unsigned long long m0 = (t < blen) ? v0 : 0ull;
      unsigned long long m1 = (t < blen) ? v1 : 0ull;
      astore64(hsdst + off, m0);
      astore64(hsdst + off + 4, m1);
      if (t == blen - 1) {
        astore64(h0b + off, v0);
        astore64(h0b + off + 4, v1);
      }
    }
  };

  unsigned hatt[4];
  auto load_hatt = [&](const bf16* h_in) {
    #pragma unroll
    for (int e = 0; e < 4; ++e)
      hatt[e] = aload32(h_in + (size_t)batt * 512 + lane * 2 + 128 * e);
  };

  unsigned hsr[8][4];

  auto attention = [&](int tprev) {
    float sc[8];
    #pragma unroll
    for (int l = 0; l < 8; ++l) {
      float p = 0.f;
      #pragma unroll
      for (int e = 0; e < 4; ++e)
        p += bflo(hatt[e]) * bflo(hsr[l][e]) + bfhi(hatt[e]) * bfhi(hsr[l][e]);
      #pragma unroll
      for (int off = 32; off; off >>= 1) p += __shfl_xor(p, off);
      sc[l] = p;
    }
    float m = -1e30f;
    #pragma unroll
    for (int l = 0; l < 8; ++l) m = fmaxf(m, (l < lenb) ? sc[l] : -1e30f);
    float wgt[8]; float den = 0.f;
    #pragma unroll
    for (int l = 0; l < 8; ++l) { wgt[l] = (l < lenb) ? expf(sc[l] - m) : 0.f; den += wgt[l]; }
    float inv = 1.f / den;
    bf16* dst = Hcat + ((size_t)tprev * 128 + batt) * 1024;
    #pragma unroll
    for (int e = 0; e < 4; ++e) {
      float clo = 0.f, chi = 0.f;
      #pragma unroll
      for (int l = 0; l < 8; ++l) {
        clo += wgt[l] * bflo(hsr[l][e]);
        chi += wgt[l] * bfhi(hsr[l][e]);
      }
      *(unsigned*)(dst + 512 + lane * 2 + 128 * e) = packbf(clo * inv, chi * inv);
      *(unsigned*)(dst + lane * 2 + 128 * e) = hatt[e];
    }
  };

  // ---------------- encoder ----------------
  loadB(WhhE);
  __syncthreads();
  for (int t = 0; t < 8; ++t) {
    prefg(preEncT + (size_t)t * 262144);   // independent of other blocks: issue early
    zacc();
    if (t > 0) {
      waitstep(flg, (unsigned)t);
      gemm_full(hS + (size_t)(t - 1) * 65536);
    }
    pointwise();
    #pragma unroll
    for (int mi = 0; mi < 2; ++mi)
      #pragma unroll
      for (int j = 0; j < 4; ++j)
        if (t == lenr[mi][j] - 1) c0r[mi][j] = cr[mi][j];
    bounce_store(hS + (size_t)t * 65536, hsEnc + (size_t)t * 65536, t, 1);
    signal(flg, blk, (unsigned)(t + 1));
  }

  // ---------------- switch to decoder ----------------
  __syncthreads();
  loadB(WhhD);
  __syncthreads();
  waitstep(flg, 8u);
  #pragma unroll
  for (int l = 0; l < 8; ++l)
    #pragma unroll
    for (int e = 0; e < 4; ++e)
      hsr[l][e] = aload32(hsEnc + ((size_t)l * 128 + batt) * 512 + lane * 2 + 128 * e);
  #pragma unroll
  for (int mi = 0; mi < 2; ++mi)
    #pragma unroll
    for (int j = 0; j < 4; ++j) cr[mi][j] = c0r[mi][j];

  // ---------------- decoder ----------------
  for (int t = 0; t < 48; ++t) {
    prefg(preDecT + (size_t)t * 262144);
    zacc();
    const bf16* hin = (t == 0) ? (const bf16*)h0b : (const bf16*)(hS + (size_t)(8 + t - 1) * 65536);
    waitstep(flg, (unsigned)(8 + t));
    gemm_full(hin);
    pointwise();
    bounce_store(hS + (size_t)(8 + t) * 65536, nullptr, t, 0);
    signal(flg, blk, (unsigned)(9 + t));
    if (t >= 1) {               // attention for step t-1, fully off critical path
      load_hatt(hin);
      attention(t - 1);
    }
  }
  waitstep(flg, 56u);
  load_hatt(hS + (size_t)55 * 65536);
  attention(47);
}

// ---------------------------------------------------------------------------
extern "C" void kernel_launch(void* const* d_in, const int* in_sizes, int n_in,
                              void* d_out, int out_size, void* d_ws, size_t ws_size,
                              hipStream_t stream)
{
  const int* kws  = (const int*)d_in[0];
  const int* poem = (const int*)d_in[1];
  const int* kwl  = (const int*)d_in[2];
  const float* emb  = (const float*)d_in[3];
  const float* eWih = (const float*)d_in[4];
  const float* eWhh = (const float*)d_in[5];
  const float* eb   = (const float*)d_in[6];
  const float* dWih = (const float*)d_in[7];
  const float* dWhh = (const float*)d_in[8];
  const float* db   = (const float*)d_in[9];
  const float* outW = (const float*)d_in[10];
  const float* outb = (const float*)d_in[11];
  float* out = (float*)d_out;

  char* base = (char*)d_ws;
  size_t o = 0;
  auto take = [&](size_t bytes) -> char* {
    char* r = base + o;
    o += (bytes + 255) & ~(size_t)255;
    return r;
  };
  bf16* WihE  = (bf16*)take(2048 * 512 * 2);
  bf16* WhhE  = (bf16*)take(2048 * 512 * 2);
  bf16* WihD  = (bf16*)take(2048 * 512 * 2);
  bf16* WhhD  = (bf16*)take(2048 * 512 * 2);
  bf16* outWb = (bf16*)take((size_t)10112 * 1024 * 2);   // padded to 79*128 rows
  bf16* Xenc  = (bf16*)take(1024 * 512 * 2);
  bf16* Xdec  = (bf16*)take((size_t)6144 * 512 * 2);
  bf16* preEncT = (bf16*)take((size_t)8 * 2048 * 128 * 2);
  bf16* preDecT = (bf16*)take((size_t)48 * 2048 * 128 * 2);
  bf16* Hcat   = (bf16*)take((size_t)6144 * 1024 * 2);
  bf16* hS     = (bf16*)take((size_t)56 * 65536 * 2);
  bf16* hsEnc  = (bf16*)take((size_t)8 * 128 * 512 * 2);
  bf16* h0b    = (bf16*)take(128 * 512 * 2);
  unsigned* flg = (unsigned*)take(4096);

  prep_kernel<<<4096, 256, 0, stream>>>(kws, poem, emb, eWih, eWhh, dWih, dWhh, outW,
                                        WihE, WhhE, WihD, WhhD, outWb, Xenc, Xdec, flg);

  // pre-gates (bias folded), stored transposed [t][2048][128]
  gemm2_kernel<3><<<128, 256, 0, stream>>>(Xenc, WihE, eb, preEncT, 1024, 2048, 512, 8);
  gemm2_kernel<3><<<768, 256, 0, stream>>>(Xdec, WihD, db, preDecT, 6144, 2048, 512, 48);

  // persistent encoder + decoder + attention
  recurrent_kernel<<<NBLK_REC, 256, 0, stream>>>(preEncT, preDecT, WhhE, WhhD, kwl,
                                                 hS, h0b, hsEnc, Hcat, flg);

  // final projection: [h|ctx] @ out_W^T + out_b, scattered to [B,T,V]
  gemm2_kernel<2><<<3792, 256, 0, stream>>>(Hcat, outWb, outb, out, 6144, 10000, 1024, 48);
}